// Round 3
// baseline (1508.335 us; speedup 1.0000x reference)
//
#include <hip/hip_runtime.h>
#include <math.h>

#define D 128

// ---------------- CSR build (XCD-partitioned: blockIdx%8 -> dst range) ----------------

__global__ void k_init_deg(int* deg, int N) {
    int i = blockIdx.x * blockDim.x + threadIdx.x;
    if (i < N) deg[i] = 1;   // self-loop pre-counted
}

__global__ void k_count(const int* __restrict__ ei, int E, int N, int* deg) {
    int part = blockIdx.x & 7;
    int slice = blockIdx.x >> 3;
    int nsl = gridDim.x >> 3;
    int lo = (int)((long long)N * part >> 3);
    int hi = (int)((long long)N * (part + 1) >> 3);
    const int* dst = ei + E;
    for (int i = slice * blockDim.x + threadIdx.x; i < E; i += nsl * blockDim.x) {
        int d = dst[i];
        if (d >= lo && d < hi) atomicAdd(&deg[d], 1);
    }
}

__global__ void k_scan1(const int* __restrict__ deg, int N, int* tmp, int* bsum) {
    __shared__ int sh[256];
    int t = threadIdx.x;
    int i = blockIdx.x * 256 + t;
    int v = (i < N) ? deg[i] : 0;
    sh[t] = v;
    __syncthreads();
    for (int o = 1; o < 256; o <<= 1) {
        int u = (t >= o) ? sh[t - o] : 0;
        __syncthreads();
        sh[t] += u;
        __syncthreads();
    }
    if (i < N) tmp[i] = sh[t] - v;          // exclusive
    if (t == 255) bsum[blockIdx.x] = sh[255];
}

__global__ void k_scan2(int* bsum, int B) {
    __shared__ int sh[256];
    int t = threadIdx.x;
    int v = (t < B) ? bsum[t] : 0;
    sh[t] = v;
    __syncthreads();
    for (int o = 1; o < 256; o <<= 1) {
        int u = (t >= o) ? sh[t - o] : 0;
        __syncthreads();
        sh[t] += u;
        __syncthreads();
    }
    bsum[t] = sh[t] - v;                    // exclusive scan of block sums
}

__global__ void k_scan3(const int* __restrict__ tmp, const int* __restrict__ bscan,
                        int N, int total, int* rowptr, int* fill) {
    int i = blockIdx.x * blockDim.x + threadIdx.x;
    if (i < N) {
        int r = tmp[i] + bscan[i >> 8];
        rowptr[i] = r;
        fill[i] = r;
    }
    if (i == 0) rowptr[N] = total;
}

__global__ void k_fill(const int* __restrict__ ei, int E, int N, int* fill, int* csr) {
    int part = blockIdx.x & 7;
    int slice = blockIdx.x >> 3;
    int nsl = gridDim.x >> 3;
    int lo = (int)((long long)N * part >> 3);
    int hi = (int)((long long)N * (part + 1) >> 3);
    int total = E + N;
    for (int i = slice * blockDim.x + threadIdx.x; i < total; i += nsl * blockDim.x) {
        int s_, d_;
        if (i < E) { s_ = ei[i]; d_ = ei[E + i]; }
        else       { s_ = d_ = i - E; }         // self loop
        if (d_ >= lo && d_ < hi) {
            int p = atomicAdd(&fill[d_], 1);
            csr[p] = s_;
        }
    }
}

// ---------------- expmap0 ----------------

__global__ void k_expmap(const float* __restrict__ x, float* __restrict__ out, int N) {
    int lane = threadIdx.x & 63;
    int node = blockIdx.x * (blockDim.x >> 6) + (threadIdx.x >> 6);
    if (node >= N) return;
    float2 v = *(const float2*)&x[(size_t)node * D + 2 * lane];
    float ss = v.x * v.x + v.y * v.y;
    for (int o = 32; o; o >>= 1) ss += __shfl_xor(ss, o, 64);
    float n = sqrtf(ss);
    n = fmaxf(n, 1e-15f);
    float sc = tanhf(n) / n;
    float2 r;
    r.x = v.x * sc;
    r.y = v.y * sc;
    *(float2*)&out[(size_t)node * D + 2 * lane] = r;
}

// ---------------- fp32 GEMM + fused attention dots ----------------
// H = A @ W; sA = H@a_src; dA = H@a_dst  (dots reduced in-register)

__global__ __launch_bounds__(256, 2) void k_gemm(const float* __restrict__ A,
                                                 const float* __restrict__ W,
                                                 const float* __restrict__ avS,
                                                 const float* __restrict__ avD,
                                                 float* __restrict__ H,
                                                 float* __restrict__ sA,
                                                 float* __restrict__ dA, int N) {
    __shared__ float Wsh[D * D];
    __shared__ float Ash[32 * D];
    int t = threadIdx.x;
    int row0 = blockIdx.x * 32;
    for (int k = 0; k < D * D; k += 256) Wsh[k + t] = W[k + t];
    for (int k = 0; k < 32 * D; k += 256) {
        int idx = k + t;
        int r = row0 + (idx >> 7);
        Ash[idx] = (r < N) ? A[(size_t)row0 * D + idx] : 0.f;
    }
    __syncthreads();
    int c0 = (t & 31) * 4;
    int r0 = (t >> 5) * 4;
    float acc[4][4] = {};
#pragma unroll 4
    for (int k = 0; k < D; k++) {
        float4 w = *(const float4*)&Wsh[k * D + c0];
        float a0 = Ash[(r0 + 0) * D + k];
        float a1 = Ash[(r0 + 1) * D + k];
        float a2 = Ash[(r0 + 2) * D + k];
        float a3 = Ash[(r0 + 3) * D + k];
        acc[0][0] += a0 * w.x; acc[0][1] += a0 * w.y; acc[0][2] += a0 * w.z; acc[0][3] += a0 * w.w;
        acc[1][0] += a1 * w.x; acc[1][1] += a1 * w.y; acc[1][2] += a1 * w.z; acc[1][3] += a1 * w.w;
        acc[2][0] += a2 * w.x; acc[2][1] += a2 * w.y; acc[2][2] += a2 * w.z; acc[2][3] += a2 * w.w;
        acc[3][0] += a3 * w.x; acc[3][1] += a3 * w.y; acc[3][2] += a3 * w.z; acc[3][3] += a3 * w.w;
    }
    for (int r = 0; r < 4; r++) {
        int gr = row0 + r0 + r;
        if (gr < N) {
            float4 o;
            o.x = acc[r][0]; o.y = acc[r][1]; o.z = acc[r][2]; o.w = acc[r][3];
            *(float4*)&H[(size_t)gr * D + c0] = o;
        }
    }
    // fused dots: s[row] = sum_c h[row][c]*avS[c]; reduce across the 32 lanes sharing r0
    float4 as4 = *(const float4*)&avS[c0];
    float4 ad4 = *(const float4*)&avD[c0];
    float ps[4], pd[4];
    for (int r = 0; r < 4; r++) {
        ps[r] = acc[r][0] * as4.x + acc[r][1] * as4.y + acc[r][2] * as4.z + acc[r][3] * as4.w;
        pd[r] = acc[r][0] * ad4.x + acc[r][1] * ad4.y + acc[r][2] * ad4.z + acc[r][3] * ad4.w;
    }
    for (int o = 1; o < 32; o <<= 1) {
        for (int r = 0; r < 4; r++) {
            ps[r] += __shfl_xor(ps[r], o, 64);
            pd[r] += __shfl_xor(pd[r], o, 64);
        }
    }
    if ((t & 31) == 0) {
        for (int r = 0; r < 4; r++) {
            int gr = row0 + r0 + r;
            if (gr < N) { sA[gr] = ps[r]; dA[gr] = pd[r]; }
        }
    }
}

// ---------------- per-dst softmax: write normalized alpha per edge ----------------

__global__ void k_soft(const float* __restrict__ sA, const float* __restrict__ dA,
                       const int* __restrict__ rowptr, const int* __restrict__ csr,
                       float* __restrict__ alpha, int N) {
    int lane = threadIdx.x & 63;
    int node = blockIdx.x * (blockDim.x >> 6) + (threadIdx.x >> 6);
    if (node >= N) return;
    int start = rowptr[node];
    int end = rowptr[node + 1];
    float di = dA[node];

    float m = -3.4e38f;
    float den = 0.f;
    // pass 1: online max+den, stash raw e into alpha
    for (int j0 = start; j0 < end; j0 += 64) {
        int j = j0 + lane;
        float e = -3.4e38f;
        if (j < end) {
            e = sA[csr[j]] + di;
            e = (e > 0.f) ? e : 0.2f * e;
            alpha[j] = e;
        }
        float cm = e;
        for (int o = 32; o; o >>= 1) cm = fmaxf(cm, __shfl_xor(cm, o, 64));
        float mnew = fmaxf(m, cm);
        float fac = __expf(m - mnew);
        float p = (j < end) ? __expf(e - mnew) : 0.f;
        float cd = p;
        for (int o = 32; o; o >>= 1) cd += __shfl_xor(cd, o, 64);
        den = den * fac + cd;
        m = mnew;
    }
    float inv = 1.f / den;
    // pass 2: normalize (alpha buffer is L2-hot)
    for (int j0 = start; j0 < end; j0 += 64) {
        int j = j0 + lane;
        if (j < end) alpha[j] = __expf(alpha[j] - m) * inv;
    }
}

// ---------------- column-sliced aggregation ----------------
// blockIdx&7 = col-group (16 cols) -> lands on one XCD (round-robin %8):
// that XCD only touches H[:,16cg:16cg+16] = 3.2MB, L2-resident -> gathers hit L2.
// wave handles one dst node: lane = eslot(4 edges)*16 + col(16).

template <bool ACT>
__global__ __launch_bounds__(256) void k_agg(const float* __restrict__ H,
                                             const float* __restrict__ alpha,
                                             const int* __restrict__ rowptr,
                                             const int* __restrict__ csr,
                                             const float* __restrict__ bias,
                                             float* __restrict__ out, int N) {
    int cg = blockIdx.x & 7;
    int c0 = cg * 16;
    int wave = threadIdx.x >> 6;
    int lane = threadIdx.x & 63;
    int node = (blockIdx.x >> 3) * 4 + wave;
    if (node >= N) return;
    int col = lane & 15;
    int eslot = lane >> 4;
    int start = rowptr[node];
    int end = rowptr[node + 1];

    float acc = 0.f;
    for (int j0 = start; j0 < end; j0 += 4) {
        int j = j0 + eslot;
        if (j < end) {
            int sj = csr[j];          // 16 lanes same addr -> HW broadcast
            float w = alpha[j];
            acc += w * H[(size_t)sj * D + c0 + col];   // 64B contiguous per eslot group
        }
    }
    acc += __shfl_xor(acc, 16, 64);
    acc += __shfl_xor(acc, 32, 64);

    float v = acc + bias[c0 + col];
    if (ACT) v = 2.f * tanhf(v);
    if (lane < 16) out[(size_t)node * D + c0 + col] = v;
}

// ---------------- launch ----------------

extern "C" void kernel_launch(void* const* d_in, const int* in_sizes, int n_in,
                              void* d_out, int out_size, void* d_ws, size_t ws_size,
                              hipStream_t stream) {
    const int N = in_sizes[0] / D;
    const int E = in_sizes[1] / 2;
    const float* x = (const float*)d_in[0];
    const int* ei = (const int*)d_in[1];
    const float* Wm[3] = {(const float*)d_in[2], (const float*)d_in[6], (const float*)d_in[10]};
    const float* aS[3] = {(const float*)d_in[3], (const float*)d_in[7], (const float*)d_in[11]};
    const float* aD[3] = {(const float*)d_in[4], (const float*)d_in[8], (const float*)d_in[12]};
    const float* bb[3] = {(const float*)d_in[5], (const float*)d_in[9], (const float*)d_in[13]};

    char* ws = (char*)d_ws;
    size_t off = 0;
    auto alloc = [&](size_t bytes) -> void* {
        void* p = ws + off;
        off = (off + bytes + 511) & ~(size_t)511;
        return p;
    };
    float* bufA  = (float*)alloc((size_t)N * D * 4);
    float* bufB  = (float*)alloc((size_t)N * D * 4);
    float* sArr  = (float*)alloc((size_t)N * 4);
    float* dArr  = (float*)alloc((size_t)N * 4);
    int*   deg   = (int*)alloc((size_t)N * 4);       // reused as fill cursor
    int*   rowptr= (int*)alloc((size_t)(N + 1) * 4);
    int*   tmp   = (int*)alloc((size_t)N * 4);
    int*   bsum  = (int*)alloc(256 * 4);
    int*   csr   = (int*)alloc((size_t)(E + N) * 4);
    float* alpha = (float*)alloc((size_t)(E + N) * 4);
    (void)ws_size; (void)n_in; (void)out_size;

    const int B1 = (N + 255) / 256;

    k_init_deg<<<B1, 256, 0, stream>>>(deg, N);
    k_count<<<1024, 256, 0, stream>>>(ei, E, N, deg);
    k_scan1<<<B1, 256, 0, stream>>>(deg, N, tmp, bsum);
    k_scan2<<<1, 256, 0, stream>>>(bsum, B1);
    k_scan3<<<B1, 256, 0, stream>>>(tmp, bsum, N, E + N, rowptr, deg);
    k_fill<<<1024, 256, 0, stream>>>(ei, E, N, deg, csr);

    k_expmap<<<(N + 3) / 4, 256, 0, stream>>>(x, bufA, N);

    const int aggBlocks = 8 * ((N + 3) / 4);
    for (int l = 0; l < 3; l++) {
        k_gemm<<<(N + 31) / 32, 256, 0, stream>>>(bufA, Wm[l], aS[l], aD[l],
                                                  bufB, sArr, dArr, N);
        k_soft<<<(N + 3) / 4, 256, 0, stream>>>(sArr, dArr, rowptr, csr, alpha, N);
        if (l < 2) {
            k_agg<true><<<aggBlocks, 256, 0, stream>>>(bufB, alpha, rowptr, csr,
                                                       bb[l], bufA, N);
        } else {
            k_agg<false><<<aggBlocks, 256, 0, stream>>>(bufB, alpha, rowptr, csr,
                                                        bb[l], (float*)d_out, N);
        }
    }
}

// Round 4
// 778.275 us; speedup vs baseline: 1.9380x; 1.9380x over previous
//
#include <hip/hip_runtime.h>
#include <math.h>

#define D 128

// ---------------- CSR build (XCD-partitioned: blockIdx%8 -> dst range) ----------------

__global__ void k_init_deg(int* deg, int N) {
    int i = blockIdx.x * blockDim.x + threadIdx.x;
    if (i < N) deg[i] = 1;   // self-loop pre-counted
}

__global__ void k_count(const int* __restrict__ ei, int E, int N, int* deg) {
    int part = blockIdx.x & 7;
    int slice = blockIdx.x >> 3;
    int nsl = gridDim.x >> 3;
    int lo = (int)((long long)N * part >> 3);
    int hi = (int)((long long)N * (part + 1) >> 3);
    const int* dst = ei + E;
    for (int i = slice * blockDim.x + threadIdx.x; i < E; i += nsl * blockDim.x) {
        int d = dst[i];
        if (d >= lo && d < hi) atomicAdd(&deg[d], 1);
    }
}

__global__ void k_scan1(const int* __restrict__ deg, int N, int* tmp, int* bsum) {
    __shared__ int sh[256];
    int t = threadIdx.x;
    int i = blockIdx.x * 256 + t;
    int v = (i < N) ? deg[i] : 0;
    sh[t] = v;
    __syncthreads();
    for (int o = 1; o < 256; o <<= 1) {
        int u = (t >= o) ? sh[t - o] : 0;
        __syncthreads();
        sh[t] += u;
        __syncthreads();
    }
    if (i < N) tmp[i] = sh[t] - v;          // exclusive
    if (t == 255) bsum[blockIdx.x] = sh[255];
}

__global__ void k_scan2(int* bsum, int B) {
    __shared__ int sh[256];
    int t = threadIdx.x;
    int v = (t < B) ? bsum[t] : 0;
    sh[t] = v;
    __syncthreads();
    for (int o = 1; o < 256; o <<= 1) {
        int u = (t >= o) ? sh[t - o] : 0;
        __syncthreads();
        sh[t] += u;
        __syncthreads();
    }
    bsum[t] = sh[t] - v;                    // exclusive scan of block sums
}

__global__ void k_scan3(const int* __restrict__ tmp, const int* __restrict__ bscan,
                        int N, int total, int* rowptr, int* fill) {
    int i = blockIdx.x * blockDim.x + threadIdx.x;
    if (i < N) {
        int r = tmp[i] + bscan[i >> 8];
        rowptr[i] = r;
        fill[i] = r;
    }
    if (i == 0) rowptr[N] = total;
}

__global__ void k_fill(const int* __restrict__ ei, int E, int N, int* fill, int* csr) {
    int part = blockIdx.x & 7;
    int slice = blockIdx.x >> 3;
    int nsl = gridDim.x >> 3;
    int lo = (int)((long long)N * part >> 3);
    int hi = (int)((long long)N * (part + 1) >> 3);
    int total = E + N;
    for (int i = slice * blockDim.x + threadIdx.x; i < total; i += nsl * blockDim.x) {
        int s_, d_;
        if (i < E) { s_ = ei[i]; d_ = ei[E + i]; }
        else       { s_ = d_ = i - E; }         // self loop
        if (d_ >= lo && d_ < hi) {
            int p = atomicAdd(&fill[d_], 1);
            csr[p] = s_;
        }
    }
}

// ---------------- expmap0 ----------------

__global__ void k_expmap(const float* __restrict__ x, float* __restrict__ out, int N) {
    int lane = threadIdx.x & 63;
    int node = blockIdx.x * (blockDim.x >> 6) + (threadIdx.x >> 6);
    if (node >= N) return;
    float2 v = *(const float2*)&x[(size_t)node * D + 2 * lane];
    float ss = v.x * v.x + v.y * v.y;
    for (int o = 32; o; o >>= 1) ss += __shfl_xor(ss, o, 64);
    float n = sqrtf(ss);
    n = fmaxf(n, 1e-15f);
    float sc = tanhf(n) / n;
    float2 r;
    r.x = v.x * sc;
    r.y = v.y * sc;
    *(float2*)&out[(size_t)node * D + 2 * lane] = r;
}

// ---------------- fp32 GEMM + fused attention dots ----------------

__global__ __launch_bounds__(256, 2) void k_gemm(const float* __restrict__ A,
                                                 const float* __restrict__ W,
                                                 const float* __restrict__ avS,
                                                 const float* __restrict__ avD,
                                                 float* __restrict__ H,
                                                 float* __restrict__ sA,
                                                 float* __restrict__ dA, int N) {
    __shared__ float Wsh[D * D];
    __shared__ float Ash[32 * D];
    int t = threadIdx.x;
    int row0 = blockIdx.x * 32;
    for (int k = 0; k < D * D; k += 256) Wsh[k + t] = W[k + t];
    for (int k = 0; k < 32 * D; k += 256) {
        int idx = k + t;
        int r = row0 + (idx >> 7);
        Ash[idx] = (r < N) ? A[(size_t)row0 * D + idx] : 0.f;
    }
    __syncthreads();
    int c0 = (t & 31) * 4;
    int r0 = (t >> 5) * 4;
    float acc[4][4] = {};
#pragma unroll 4
    for (int k = 0; k < D; k++) {
        float4 w = *(const float4*)&Wsh[k * D + c0];
        float a0 = Ash[(r0 + 0) * D + k];
        float a1 = Ash[(r0 + 1) * D + k];
        float a2 = Ash[(r0 + 2) * D + k];
        float a3 = Ash[(r0 + 3) * D + k];
        acc[0][0] += a0 * w.x; acc[0][1] += a0 * w.y; acc[0][2] += a0 * w.z; acc[0][3] += a0 * w.w;
        acc[1][0] += a1 * w.x; acc[1][1] += a1 * w.y; acc[1][2] += a1 * w.z; acc[1][3] += a1 * w.w;
        acc[2][0] += a2 * w.x; acc[2][1] += a2 * w.y; acc[2][2] += a2 * w.z; acc[2][3] += a2 * w.w;
        acc[3][0] += a3 * w.x; acc[3][1] += a3 * w.y; acc[3][2] += a3 * w.z; acc[3][3] += a3 * w.w;
    }
    for (int r = 0; r < 4; r++) {
        int gr = row0 + r0 + r;
        if (gr < N) {
            float4 o;
            o.x = acc[r][0]; o.y = acc[r][1]; o.z = acc[r][2]; o.w = acc[r][3];
            *(float4*)&H[(size_t)gr * D + c0] = o;
        }
    }
    float4 as4 = *(const float4*)&avS[c0];
    float4 ad4 = *(const float4*)&avD[c0];
    float ps[4], pd[4];
    for (int r = 0; r < 4; r++) {
        ps[r] = acc[r][0] * as4.x + acc[r][1] * as4.y + acc[r][2] * as4.z + acc[r][3] * as4.w;
        pd[r] = acc[r][0] * ad4.x + acc[r][1] * ad4.y + acc[r][2] * ad4.z + acc[r][3] * ad4.w;
    }
    for (int o = 1; o < 32; o <<= 1) {
        for (int r = 0; r < 4; r++) {
            ps[r] += __shfl_xor(ps[r], o, 64);
            pd[r] += __shfl_xor(pd[r], o, 64);
        }
    }
    if ((t & 31) == 0) {
        for (int r = 0; r < 4; r++) {
            int gr = row0 + r0 + r;
            if (gr < N) { sA[gr] = ps[r]; dA[gr] = pd[r]; }
        }
    }
}

// ---------------- per-dst softmax: write normalized alpha per edge ----------------

__global__ void k_soft(const float* __restrict__ sA, const float* __restrict__ dA,
                       const int* __restrict__ rowptr, const int* __restrict__ csr,
                       float* __restrict__ alpha, int N) {
    int lane = threadIdx.x & 63;
    int node = blockIdx.x * (blockDim.x >> 6) + (threadIdx.x >> 6);
    if (node >= N) return;
    int start = rowptr[node];
    int end = rowptr[node + 1];
    float di = dA[node];

    float m = -3.4e38f;
    float den = 0.f;
    for (int j0 = start; j0 < end; j0 += 64) {
        int j = j0 + lane;
        float e = -3.4e38f;
        if (j < end) {
            e = sA[csr[j]] + di;
            e = (e > 0.f) ? e : 0.2f * e;
            alpha[j] = e;
        }
        float cm = e;
        for (int o = 32; o; o >>= 1) cm = fmaxf(cm, __shfl_xor(cm, o, 64));
        float mnew = fmaxf(m, cm);
        float fac = __expf(m - mnew);
        float p = (j < end) ? __expf(e - mnew) : 0.f;
        float cd = p;
        for (int o = 32; o; o >>= 1) cd += __shfl_xor(cd, o, 64);
        den = den * fac + cd;
        m = mnew;
    }
    float inv = 1.f / den;
    for (int j0 = start; j0 < end; j0 += 64) {
        int j = j0 + lane;
        if (j < end) alpha[j] = __expf(alpha[j] - m) * inv;
    }
}

// ---------------- aggregation: one wave per dst, scalar-pipe edge metadata ----------------
// (sj, w) are wave-uniform -> readfirstlane'd bounds + uniform index j make the
// compiler emit s_load (K$) for csr/alpha; lanes do 512B contiguous row gathers.

template <bool ACT>
__global__ __launch_bounds__(256) void k_agg(const float* __restrict__ H,
                                             const float* __restrict__ alpha,
                                             const int* __restrict__ rowptr,
                                             const int* __restrict__ csr,
                                             const float* __restrict__ bias,
                                             float* __restrict__ out, int N) {
    int lane = threadIdx.x & 63;
    int node = blockIdx.x * 4 + (threadIdx.x >> 6);
    if (node >= N) return;
    int start = __builtin_amdgcn_readfirstlane(rowptr[node]);
    int end   = __builtin_amdgcn_readfirstlane(rowptr[node + 1]);
    const int cofs = 2 * lane;

    float ax = 0.f, ay = 0.f;
    int j = start;
    for (; j + 4 <= end; j += 4) {
        int   s0 = csr[j + 0], s1 = csr[j + 1], s2 = csr[j + 2], s3 = csr[j + 3];
        float w0 = alpha[j + 0], w1 = alpha[j + 1], w2 = alpha[j + 2], w3 = alpha[j + 3];
        float2 h0 = *(const float2*)&H[(size_t)s0 * D + cofs];
        float2 h1 = *(const float2*)&H[(size_t)s1 * D + cofs];
        float2 h2 = *(const float2*)&H[(size_t)s2 * D + cofs];
        float2 h3 = *(const float2*)&H[(size_t)s3 * D + cofs];
        ax += w0 * h0.x; ay += w0 * h0.y;
        ax += w1 * h1.x; ay += w1 * h1.y;
        ax += w2 * h2.x; ay += w2 * h2.y;
        ax += w3 * h3.x; ay += w3 * h3.y;
    }
    for (; j < end; j++) {
        int s0 = csr[j];
        float w0 = alpha[j];
        float2 h0 = *(const float2*)&H[(size_t)s0 * D + cofs];
        ax += w0 * h0.x; ay += w0 * h0.y;
    }

    float2 b2 = *(const float2*)&bias[cofs];
    float vx = ax + b2.x;
    float vy = ay + b2.y;
    if (ACT) {
        vx = 2.f * tanhf(vx);
        vy = 2.f * tanhf(vy);
    }
    *(float2*)&out[(size_t)node * D + cofs] = make_float2(vx, vy);
}

// ---------------- launch ----------------

extern "C" void kernel_launch(void* const* d_in, const int* in_sizes, int n_in,
                              void* d_out, int out_size, void* d_ws, size_t ws_size,
                              hipStream_t stream) {
    const int N = in_sizes[0] / D;
    const int E = in_sizes[1] / 2;
    const float* x = (const float*)d_in[0];
    const int* ei = (const int*)d_in[1];
    const float* Wm[3] = {(const float*)d_in[2], (const float*)d_in[6], (const float*)d_in[10]};
    const float* aS[3] = {(const float*)d_in[3], (const float*)d_in[7], (const float*)d_in[11]};
    const float* aD[3] = {(const float*)d_in[4], (const float*)d_in[8], (const float*)d_in[12]};
    const float* bb[3] = {(const float*)d_in[5], (const float*)d_in[9], (const float*)d_in[13]};

    char* ws = (char*)d_ws;
    size_t off = 0;
    auto alloc = [&](size_t bytes) -> void* {
        void* p = ws + off;
        off = (off + bytes + 511) & ~(size_t)511;
        return p;
    };
    float* bufA  = (float*)alloc((size_t)N * D * 4);
    float* bufB  = (float*)alloc((size_t)N * D * 4);
    float* sArr  = (float*)alloc((size_t)N * 4);
    float* dArr  = (float*)alloc((size_t)N * 4);
    int*   deg   = (int*)alloc((size_t)N * 4);
    int*   rowptr= (int*)alloc((size_t)(N + 1) * 4);
    int*   tmp   = (int*)alloc((size_t)N * 4);
    int*   bsum  = (int*)alloc(256 * 4);
    int*   csr   = (int*)alloc((size_t)(E + N) * 4);
    float* alpha = (float*)alloc((size_t)(E + N) * 4);
    (void)ws_size; (void)n_in; (void)out_size;

    const int B1 = (N + 255) / 256;

    k_init_deg<<<B1, 256, 0, stream>>>(deg, N);
    k_count<<<1024, 256, 0, stream>>>(ei, E, N, deg);
    k_scan1<<<B1, 256, 0, stream>>>(deg, N, tmp, bsum);
    k_scan2<<<1, 256, 0, stream>>>(bsum, B1);
    k_scan3<<<B1, 256, 0, stream>>>(tmp, bsum, N, E + N, rowptr, deg);
    k_fill<<<1024, 256, 0, stream>>>(ei, E, N, deg, csr);

    k_expmap<<<(N + 3) / 4, 256, 0, stream>>>(x, bufA, N);

    for (int l = 0; l < 3; l++) {
        k_gemm<<<(N + 31) / 32, 256, 0, stream>>>(bufA, Wm[l], aS[l], aD[l],
                                                  bufB, sArr, dArr, N);
        k_soft<<<(N + 3) / 4, 256, 0, stream>>>(sArr, dArr, rowptr, csr, alpha, N);
        if (l < 2) {
            k_agg<true><<<(N + 3) / 4, 256, 0, stream>>>(bufB, alpha, rowptr, csr,
                                                         bb[l], bufA, N);
        } else {
            k_agg<false><<<(N + 3) / 4, 256, 0, stream>>>(bufB, alpha, rowptr, csr,
                                                          bb[l], (float*)d_out, N);
        }
    }
}

// Round 5
// 768.930 us; speedup vs baseline: 1.9616x; 1.0122x over previous
//
#include <hip/hip_runtime.h>
#include <math.h>

#define D 128

// ---------------- CSR build (XCD-partitioned: blockIdx%8 -> dst range) ----------------

__global__ void k_init_deg(int* deg, int N) {
    int i = blockIdx.x * blockDim.x + threadIdx.x;
    if (i < N) deg[i] = 1;   // self-loop pre-counted
}

__global__ void k_count(const int* __restrict__ ei, int E, int N, int* deg) {
    int part = blockIdx.x & 7;
    int slice = blockIdx.x >> 3;
    int nsl = gridDim.x >> 3;
    int lo = (int)((long long)N * part >> 3);
    int hi = (int)((long long)N * (part + 1) >> 3);
    const int* dst = ei + E;
    for (int i = slice * blockDim.x + threadIdx.x; i < E; i += nsl * blockDim.x) {
        int d = dst[i];
        if (d >= lo && d < hi) atomicAdd(&deg[d], 1);
    }
}

__global__ void k_scan1(const int* __restrict__ deg, int N, int* tmp, int* bsum) {
    __shared__ int sh[256];
    int t = threadIdx.x;
    int i = blockIdx.x * 256 + t;
    int v = (i < N) ? deg[i] : 0;
    sh[t] = v;
    __syncthreads();
    for (int o = 1; o < 256; o <<= 1) {
        int u = (t >= o) ? sh[t - o] : 0;
        __syncthreads();
        sh[t] += u;
        __syncthreads();
    }
    if (i < N) tmp[i] = sh[t] - v;          // exclusive
    if (t == 255) bsum[blockIdx.x] = sh[255];
}

__global__ void k_scan2(int* bsum, int B) {
    __shared__ int sh[256];
    int t = threadIdx.x;
    int v = (t < B) ? bsum[t] : 0;
    sh[t] = v;
    __syncthreads();
    for (int o = 1; o < 256; o <<= 1) {
        int u = (t >= o) ? sh[t - o] : 0;
        __syncthreads();
        sh[t] += u;
        __syncthreads();
    }
    bsum[t] = sh[t] - v;                    // exclusive scan of block sums
}

__global__ void k_scan3(const int* __restrict__ tmp, const int* __restrict__ bscan,
                        int N, int total, int* rowptr, int* fill) {
    int i = blockIdx.x * blockDim.x + threadIdx.x;
    if (i < N) {
        int r = tmp[i] + bscan[i >> 8];
        rowptr[i] = r;
        fill[i] = r;
    }
    if (i == 0) rowptr[N] = total;
}

__global__ void k_fill(const int* __restrict__ ei, int E, int N, int* fill, int* csr) {
    int part = blockIdx.x & 7;
    int slice = blockIdx.x >> 3;
    int nsl = gridDim.x >> 3;
    int lo = (int)((long long)N * part >> 3);
    int hi = (int)((long long)N * (part + 1) >> 3);
    int total = E + N;
    for (int i = slice * blockDim.x + threadIdx.x; i < total; i += nsl * blockDim.x) {
        int s_, d_;
        if (i < E) { s_ = ei[i]; d_ = ei[E + i]; }
        else       { s_ = d_ = i - E; }         // self loop
        if (d_ >= lo && d_ < hi) {
            int p = atomicAdd(&fill[d_], 1);
            csr[p] = s_;
        }
    }
}

// ---------------- expmap0 ----------------

__global__ void k_expmap(const float* __restrict__ x, float* __restrict__ out, int N) {
    int lane = threadIdx.x & 63;
    int node = blockIdx.x * (blockDim.x >> 6) + (threadIdx.x >> 6);
    if (node >= N) return;
    float2 v = *(const float2*)&x[(size_t)node * D + 2 * lane];
    float ss = v.x * v.x + v.y * v.y;
    for (int o = 32; o; o >>= 1) ss += __shfl_xor(ss, o, 64);
    float n = sqrtf(ss);
    n = fmaxf(n, 1e-15f);
    float sc = tanhf(n) / n;
    float2 r;
    r.x = v.x * sc;
    r.y = v.y * sc;
    *(float2*)&out[(size_t)node * D + 2 * lane] = r;
}

// ---------------- fp32 GEMM + fused attention dots ----------------

__global__ __launch_bounds__(256, 2) void k_gemm(const float* __restrict__ A,
                                                 const float* __restrict__ W,
                                                 const float* __restrict__ avS,
                                                 const float* __restrict__ avD,
                                                 float* __restrict__ H,
                                                 float* __restrict__ sA,
                                                 float* __restrict__ dA, int N) {
    __shared__ float Wsh[D * D];
    __shared__ float Ash[32 * D];
    int t = threadIdx.x;
    int row0 = blockIdx.x * 32;
    for (int k = 0; k < D * D; k += 256) Wsh[k + t] = W[k + t];
    for (int k = 0; k < 32 * D; k += 256) {
        int idx = k + t;
        int r = row0 + (idx >> 7);
        Ash[idx] = (r < N) ? A[(size_t)row0 * D + idx] : 0.f;
    }
    __syncthreads();
    int c0 = (t & 31) * 4;
    int r0 = (t >> 5) * 4;
    float acc[4][4] = {};
#pragma unroll 4
    for (int k = 0; k < D; k++) {
        float4 w = *(const float4*)&Wsh[k * D + c0];
        float a0 = Ash[(r0 + 0) * D + k];
        float a1 = Ash[(r0 + 1) * D + k];
        float a2 = Ash[(r0 + 2) * D + k];
        float a3 = Ash[(r0 + 3) * D + k];
        acc[0][0] += a0 * w.x; acc[0][1] += a0 * w.y; acc[0][2] += a0 * w.z; acc[0][3] += a0 * w.w;
        acc[1][0] += a1 * w.x; acc[1][1] += a1 * w.y; acc[1][2] += a1 * w.z; acc[1][3] += a1 * w.w;
        acc[2][0] += a2 * w.x; acc[2][1] += a2 * w.y; acc[2][2] += a2 * w.z; acc[2][3] += a2 * w.w;
        acc[3][0] += a3 * w.x; acc[3][1] += a3 * w.y; acc[3][2] += a3 * w.z; acc[3][3] += a3 * w.w;
    }
    for (int r = 0; r < 4; r++) {
        int gr = row0 + r0 + r;
        if (gr < N) {
            float4 o;
            o.x = acc[r][0]; o.y = acc[r][1]; o.z = acc[r][2]; o.w = acc[r][3];
            *(float4*)&H[(size_t)gr * D + c0] = o;
        }
    }
    float4 as4 = *(const float4*)&avS[c0];
    float4 ad4 = *(const float4*)&avD[c0];
    float ps[4], pd[4];
    for (int r = 0; r < 4; r++) {
        ps[r] = acc[r][0] * as4.x + acc[r][1] * as4.y + acc[r][2] * as4.z + acc[r][3] * as4.w;
        pd[r] = acc[r][0] * ad4.x + acc[r][1] * ad4.y + acc[r][2] * ad4.z + acc[r][3] * ad4.w;
    }
    for (int o = 1; o < 32; o <<= 1) {
        for (int r = 0; r < 4; r++) {
            ps[r] += __shfl_xor(ps[r], o, 64);
            pd[r] += __shfl_xor(pd[r], o, 64);
        }
    }
    if ((t & 31) == 0) {
        for (int r = 0; r < 4; r++) {
            int gr = row0 + r0 + r;
            if (gr < N) { sA[gr] = ps[r]; dA[gr] = pd[r]; }
        }
    }
}

// ---------------- per-dst softmax, single pass (no max shift; |e|<~72 is fp32-safe) ----
// writes UNNORMALIZED alpha=exp(e) and inv[node]=1/den; k_agg scales at the end.

__global__ void k_soft(const float* __restrict__ sA, const float* __restrict__ dA,
                       const int* __restrict__ rowptr, const int* __restrict__ csr,
                       float* __restrict__ alpha, float* __restrict__ invArr, int N) {
    int lane = threadIdx.x & 63;
    int node = blockIdx.x * (blockDim.x >> 6) + (threadIdx.x >> 6);
    if (node >= N) return;
    int start = rowptr[node];
    int end = rowptr[node + 1];
    float di = dA[node];

    float den = 0.f;
    for (int j0 = start; j0 < end; j0 += 64) {
        int j = j0 + lane;
        if (j < end) {
            float e = sA[csr[j]] + di;
            e = (e > 0.f) ? e : 0.2f * e;
            float p = __expf(e);
            alpha[j] = p;
            den += p;
        }
    }
    for (int o = 32; o; o >>= 1) den += __shfl_xor(den, o, 64);
    if (lane == 0) invArr[node] = 1.f / den;
}

// ---------------- aggregation: one wave per dst, 2 edges per memory instruction -------
// lanes 0-31 gather edge j's H row (float4 each = 512B), lanes 32-63 edge j+1's row.
// csr/alpha metadata via wave-uniform scalar loads (K$); halves request count vs R4.

template <bool ACT>
__global__ __launch_bounds__(256) void k_agg(const float* __restrict__ H,
                                             const float* __restrict__ alpha,
                                             const float* __restrict__ invArr,
                                             const int* __restrict__ rowptr,
                                             const int* __restrict__ csr,
                                             const float* __restrict__ bias,
                                             float* __restrict__ out, int N) {
    int lane = threadIdx.x & 63;
    int node = blockIdx.x * 4 + (threadIdx.x >> 6);
    if (node >= N) return;
    int start = __builtin_amdgcn_readfirstlane(rowptr[node]);
    int end   = __builtin_amdgcn_readfirstlane(rowptr[node + 1]);
    int half  = lane >> 5;             // 0: even edge, 1: odd edge
    int cq    = (lane & 31) * 4;       // this lane's 4-col group

    float ax = 0.f, ay = 0.f, az = 0.f, aw = 0.f;
    int j = start;
    for (; j + 4 <= end; j += 4) {
        int   s0 = csr[j + 0], s1 = csr[j + 1], s2 = csr[j + 2], s3 = csr[j + 3];
        float w0 = alpha[j + 0], w1 = alpha[j + 1], w2 = alpha[j + 2], w3 = alpha[j + 3];
        int   sa = half ? s1 : s0;
        int   sb = half ? s3 : s2;
        float wa = half ? w1 : w0;
        float wb = half ? w3 : w2;
        float4 ha = *(const float4*)&H[(size_t)sa * D + cq];
        float4 hb = *(const float4*)&H[(size_t)sb * D + cq];
        ax += wa * ha.x + wb * hb.x;
        ay += wa * ha.y + wb * hb.y;
        az += wa * ha.z + wb * hb.z;
        aw += wa * ha.w + wb * hb.w;
    }
    if (j + 2 <= end) {
        int   s0 = csr[j + 0], s1 = csr[j + 1];
        float w0 = alpha[j + 0], w1 = alpha[j + 1];
        int   sa = half ? s1 : s0;
        float wa = half ? w1 : w0;
        float4 ha = *(const float4*)&H[(size_t)sa * D + cq];
        ax += wa * ha.x; ay += wa * ha.y; az += wa * ha.z; aw += wa * ha.w;
        j += 2;
    }
    if (j < end && half == 0) {        // last odd edge: half 0 only
        int s0 = csr[j];
        float w0 = alpha[j];
        float4 ha = *(const float4*)&H[(size_t)s0 * D + cq];
        ax += w0 * ha.x; ay += w0 * ha.y; az += w0 * ha.z; aw += w0 * ha.w;
    }

    // fold odd-edge half into even half (same cols in lanes i and i+32)
    ax += __shfl_xor(ax, 32, 64);
    ay += __shfl_xor(ay, 32, 64);
    az += __shfl_xor(az, 32, 64);
    aw += __shfl_xor(aw, 32, 64);

    if (half == 0) {
        float iv = invArr[node];
        float4 b4 = *(const float4*)&bias[cq];
        float vx = ax * iv + b4.x;
        float vy = ay * iv + b4.y;
        float vz = az * iv + b4.z;
        float vw = aw * iv + b4.w;
        if (ACT) {
            vx = 2.f * tanhf(vx);
            vy = 2.f * tanhf(vy);
            vz = 2.f * tanhf(vz);
            vw = 2.f * tanhf(vw);
        }
        float4 o = make_float4(vx, vy, vz, vw);
        *(float4*)&out[(size_t)node * D + cq] = o;
    }
}

// ---------------- launch ----------------

extern "C" void kernel_launch(void* const* d_in, const int* in_sizes, int n_in,
                              void* d_out, int out_size, void* d_ws, size_t ws_size,
                              hipStream_t stream) {
    const int N = in_sizes[0] / D;
    const int E = in_sizes[1] / 2;
    const float* x = (const float*)d_in[0];
    const int* ei = (const int*)d_in[1];
    const float* Wm[3] = {(const float*)d_in[2], (const float*)d_in[6], (const float*)d_in[10]};
    const float* aS[3] = {(const float*)d_in[3], (const float*)d_in[7], (const float*)d_in[11]};
    const float* aD[3] = {(const float*)d_in[4], (const float*)d_in[8], (const float*)d_in[12]};
    const float* bb[3] = {(const float*)d_in[5], (const float*)d_in[9], (const float*)d_in[13]};

    char* ws = (char*)d_ws;
    size_t off = 0;
    auto alloc = [&](size_t bytes) -> void* {
        void* p = ws + off;
        off = (off + bytes + 511) & ~(size_t)511;
        return p;
    };
    float* bufA  = (float*)alloc((size_t)N * D * 4);
    float* bufB  = (float*)alloc((size_t)N * D * 4);
    float* sArr  = (float*)alloc((size_t)N * 4);
    float* dArr  = (float*)alloc((size_t)N * 4);
    float* invA  = (float*)alloc((size_t)N * 4);
    int*   deg   = (int*)alloc((size_t)N * 4);
    int*   rowptr= (int*)alloc((size_t)(N + 1) * 4);
    int*   tmp   = (int*)alloc((size_t)N * 4);
    int*   bsum  = (int*)alloc(256 * 4);
    int*   csr   = (int*)alloc((size_t)(E + N) * 4);
    float* alpha = (float*)alloc((size_t)(E + N) * 4);
    (void)ws_size; (void)n_in; (void)out_size;

    const int B1 = (N + 255) / 256;

    k_init_deg<<<B1, 256, 0, stream>>>(deg, N);
    k_count<<<1024, 256, 0, stream>>>(ei, E, N, deg);
    k_scan1<<<B1, 256, 0, stream>>>(deg, N, tmp, bsum);
    k_scan2<<<1, 256, 0, stream>>>(bsum, B1);
    k_scan3<<<B1, 256, 0, stream>>>(tmp, bsum, N, E + N, rowptr, deg);
    k_fill<<<1024, 256, 0, stream>>>(ei, E, N, deg, csr);

    k_expmap<<<(N + 3) / 4, 256, 0, stream>>>(x, bufA, N);

    for (int l = 0; l < 3; l++) {
        k_gemm<<<(N + 31) / 32, 256, 0, stream>>>(bufA, Wm[l], aS[l], aD[l],
                                                  bufB, sArr, dArr, N);
        k_soft<<<(N + 3) / 4, 256, 0, stream>>>(sArr, dArr, rowptr, csr, alpha, invA, N);
        if (l < 2) {
            k_agg<true><<<(N + 3) / 4, 256, 0, stream>>>(bufB, alpha, invA, rowptr, csr,
                                                         bb[l], bufA, N);
        } else {
            k_agg<false><<<(N + 3) / 4, 256, 0, stream>>>(bufB, alpha, invA, rowptr, csr,
                                                          bb[l], (float*)d_out, N);
        }
    }
}

// Round 6
// 756.107 us; speedup vs baseline: 1.9949x; 1.0170x over previous
//
#include <hip/hip_runtime.h>
#include <math.h>

#define D 128

// ---------------- CSR build (XCD-partitioned: blockIdx%8 -> dst range) ----------------

__global__ void k_init_deg(int* deg, int N) {
    int i = blockIdx.x * blockDim.x + threadIdx.x;
    if (i < N) deg[i] = 1;   // self-loop pre-counted
}

__global__ void k_count(const int* __restrict__ ei, int E, int N, int* deg) {
    int part = blockIdx.x & 7;
    int slice = blockIdx.x >> 3;
    int nsl = gridDim.x >> 3;
    int lo = (int)((long long)N * part >> 3);
    int hi = (int)((long long)N * (part + 1) >> 3);
    const int* dst = ei + E;
    for (int i = slice * blockDim.x + threadIdx.x; i < E; i += nsl * blockDim.x) {
        int d = dst[i];
        if (d >= lo && d < hi) atomicAdd(&deg[d], 1);
    }
}

__global__ void k_scan1(const int* __restrict__ deg, int N, int* tmp, int* bsum) {
    __shared__ int sh[256];
    int t = threadIdx.x;
    int i = blockIdx.x * 256 + t;
    int v = (i < N) ? deg[i] : 0;
    sh[t] = v;
    __syncthreads();
    for (int o = 1; o < 256; o <<= 1) {
        int u = (t >= o) ? sh[t - o] : 0;
        __syncthreads();
        sh[t] += u;
        __syncthreads();
    }
    if (i < N) tmp[i] = sh[t] - v;          // exclusive
    if (t == 255) bsum[blockIdx.x] = sh[255];
}

__global__ void k_scan2(int* bsum, int B) {
    __shared__ int sh[256];
    int t = threadIdx.x;
    int v = (t < B) ? bsum[t] : 0;
    sh[t] = v;
    __syncthreads();
    for (int o = 1; o < 256; o <<= 1) {
        int u = (t >= o) ? sh[t - o] : 0;
        __syncthreads();
        sh[t] += u;
        __syncthreads();
    }
    bsum[t] = sh[t] - v;                    // exclusive scan of block sums
}

__global__ void k_scan3(const int* __restrict__ tmp, const int* __restrict__ bscan,
                        int N, int total, int* rowptr, int* fill) {
    int i = blockIdx.x * blockDim.x + threadIdx.x;
    if (i < N) {
        int r = tmp[i] + bscan[i >> 8];
        rowptr[i] = r;
        fill[i] = r;
    }
    if (i == 0) rowptr[N] = total;
}

__global__ void k_fill(const int* __restrict__ ei, int E, int N, int* fill, int* csr) {
    int part = blockIdx.x & 7;
    int slice = blockIdx.x >> 3;
    int nsl = gridDim.x >> 3;
    int lo = (int)((long long)N * part >> 3);
    int hi = (int)((long long)N * (part + 1) >> 3);
    int total = E + N;
    for (int i = slice * blockDim.x + threadIdx.x; i < total; i += nsl * blockDim.x) {
        int s_, d_;
        if (i < E) { s_ = ei[i]; d_ = ei[E + i]; }
        else       { s_ = d_ = i - E; }         // self loop
        if (d_ >= lo && d_ < hi) {
            int p = atomicAdd(&fill[d_], 1);
            csr[p] = s_;
        }
    }
}

// ---------------- fp32 GEMM (+ optional fused expmap0 on A rows) + fused dots --------

template <bool EXP>
__global__ __launch_bounds__(256, 2) void k_gemm(const float* __restrict__ A,
                                                 const float* __restrict__ W,
                                                 const float* __restrict__ avS,
                                                 const float* __restrict__ avD,
                                                 float* __restrict__ H,
                                                 float* __restrict__ sA,
                                                 float* __restrict__ dA, int N) {
    __shared__ float Wsh[D * D];
    __shared__ float Ash[32 * D];
    __shared__ float rowScale[32];
    int t = threadIdx.x;
    int row0 = blockIdx.x * 32;
    for (int k = 0; k < D * D; k += 256) Wsh[k + t] = W[k + t];
    for (int k = 0; k < 32 * D; k += 256) {
        int idx = k + t;
        int r = row0 + (idx >> 7);
        Ash[idx] = (r < N) ? A[(size_t)row0 * D + idx] : 0.f;
    }
    __syncthreads();

    if (EXP) {
        // expmap0: scale row by tanh(||row||)/||row|| (8 threads per row, shuffle reduce)
        int row = t >> 3;                    // 0..31
        int base = row * D + (t & 7) * 16;
        float ss = 0.f;
        for (int q = 0; q < 16; q++) {
            float v = Ash[base + q];
            ss += v * v;
        }
        ss += __shfl_xor(ss, 1, 64);
        ss += __shfl_xor(ss, 2, 64);
        ss += __shfl_xor(ss, 4, 64);
        if ((t & 7) == 0) {
            float n = fmaxf(sqrtf(ss), 1e-15f);
            rowScale[row] = tanhf(n) / n;
        }
        __syncthreads();
        for (int k = 0; k < 32 * D; k += 256) {
            int idx = k + t;
            Ash[idx] *= rowScale[idx >> 7];
        }
        __syncthreads();
    }

    int c0 = (t & 31) * 4;
    int r0 = (t >> 5) * 4;
    float acc[4][4] = {};
#pragma unroll 4
    for (int k = 0; k < D; k++) {
        float4 w = *(const float4*)&Wsh[k * D + c0];
        float a0 = Ash[(r0 + 0) * D + k];
        float a1 = Ash[(r0 + 1) * D + k];
        float a2 = Ash[(r0 + 2) * D + k];
        float a3 = Ash[(r0 + 3) * D + k];
        acc[0][0] += a0 * w.x; acc[0][1] += a0 * w.y; acc[0][2] += a0 * w.z; acc[0][3] += a0 * w.w;
        acc[1][0] += a1 * w.x; acc[1][1] += a1 * w.y; acc[1][2] += a1 * w.z; acc[1][3] += a1 * w.w;
        acc[2][0] += a2 * w.x; acc[2][1] += a2 * w.y; acc[2][2] += a2 * w.z; acc[2][3] += a2 * w.w;
        acc[3][0] += a3 * w.x; acc[3][1] += a3 * w.y; acc[3][2] += a3 * w.z; acc[3][3] += a3 * w.w;
    }
    for (int r = 0; r < 4; r++) {
        int gr = row0 + r0 + r;
        if (gr < N) {
            float4 o;
            o.x = acc[r][0]; o.y = acc[r][1]; o.z = acc[r][2]; o.w = acc[r][3];
            *(float4*)&H[(size_t)gr * D + c0] = o;
        }
    }
    float4 as4 = *(const float4*)&avS[c0];
    float4 ad4 = *(const float4*)&avD[c0];
    float ps[4], pd[4];
    for (int r = 0; r < 4; r++) {
        ps[r] = acc[r][0] * as4.x + acc[r][1] * as4.y + acc[r][2] * as4.z + acc[r][3] * as4.w;
        pd[r] = acc[r][0] * ad4.x + acc[r][1] * ad4.y + acc[r][2] * ad4.z + acc[r][3] * ad4.w;
    }
    for (int o = 1; o < 32; o <<= 1) {
        for (int r = 0; r < 4; r++) {
            ps[r] += __shfl_xor(ps[r], o, 64);
            pd[r] += __shfl_xor(pd[r], o, 64);
        }
    }
    if ((t & 31) == 0) {
        for (int r = 0; r < 4; r++) {
            int gr = row0 + r0 + r;
            if (gr < N) { sA[gr] = ps[r]; dA[gr] = pd[r]; }
        }
    }
}

// ---------------- fused softmax + aggregation: one wave per dst ----------------------
// Edge metadata (csr[j], sA[csr[j]]) rides the scalar pipe (wave-uniform index).
// Unnormalized p=exp(leakyrelu(s+d)) computed per lane (uniform within half-wave);
// accumulator scaled by 1/den in the epilogue. Lanes 0-31 take even edges,
// lanes 32-63 odd edges; each lane gathers a float4 (2x512B rows in flight/instr).

template <bool ACT>
__global__ __launch_bounds__(256) void k_agg(const float* __restrict__ H,
                                             const float* __restrict__ sA,
                                             const float* __restrict__ dA,
                                             const int* __restrict__ rowptr,
                                             const int* __restrict__ csr,
                                             const float* __restrict__ bias,
                                             float* __restrict__ out, int N) {
    int lane = threadIdx.x & 63;
    int node = blockIdx.x * 4 + (threadIdx.x >> 6);
    if (node >= N) return;
    int start = __builtin_amdgcn_readfirstlane(rowptr[node]);
    int end   = __builtin_amdgcn_readfirstlane(rowptr[node + 1]);
    float di  = dA[node];                  // uniform -> scalar
    int half  = lane >> 5;                 // 0: even edge, 1: odd edge
    int cq    = (lane & 31) * 4;           // this lane's 4-col group

    float ax = 0.f, ay = 0.f, az = 0.f, aw = 0.f;
    float den = 0.f;
    int j = start;
    for (; j + 4 <= end; j += 4) {
        int s0 = csr[j + 0], s1 = csr[j + 1], s2 = csr[j + 2], s3 = csr[j + 3];
        float e0 = sA[s0] + di, e1 = sA[s1] + di, e2 = sA[s2] + di, e3 = sA[s3] + di;
        e0 = (e0 > 0.f) ? e0 : 0.2f * e0;
        e1 = (e1 > 0.f) ? e1 : 0.2f * e1;
        e2 = (e2 > 0.f) ? e2 : 0.2f * e2;
        e3 = (e3 > 0.f) ? e3 : 0.2f * e3;
        float p0 = __expf(e0), p1 = __expf(e1), p2 = __expf(e2), p3 = __expf(e3);
        int   sa = half ? s1 : s0;
        int   sb = half ? s3 : s2;
        float wa = half ? p1 : p0;
        float wb = half ? p3 : p2;
        den += wa + wb;
        float4 ha = *(const float4*)&H[(size_t)sa * D + cq];
        float4 hb = *(const float4*)&H[(size_t)sb * D + cq];
        ax += wa * ha.x + wb * hb.x;
        ay += wa * ha.y + wb * hb.y;
        az += wa * ha.z + wb * hb.z;
        aw += wa * ha.w + wb * hb.w;
    }
    if (j + 2 <= end) {
        int s0 = csr[j + 0], s1 = csr[j + 1];
        float e0 = sA[s0] + di, e1 = sA[s1] + di;
        e0 = (e0 > 0.f) ? e0 : 0.2f * e0;
        e1 = (e1 > 0.f) ? e1 : 0.2f * e1;
        float p0 = __expf(e0), p1 = __expf(e1);
        int   sa = half ? s1 : s0;
        float wa = half ? p1 : p0;
        den += wa;
        float4 ha = *(const float4*)&H[(size_t)sa * D + cq];
        ax += wa * ha.x; ay += wa * ha.y; az += wa * ha.z; aw += wa * ha.w;
        j += 2;
    }
    if (j < end && half == 0) {            // last odd edge: half 0 only
        int s0 = csr[j];
        float e0 = sA[s0] + di;
        e0 = (e0 > 0.f) ? e0 : 0.2f * e0;
        float p0 = __expf(e0);
        den += p0;
        float4 ha = *(const float4*)&H[(size_t)s0 * D + cq];
        ax += p0 * ha.x; ay += p0 * ha.y; az += p0 * ha.z; aw += p0 * ha.w;
    }

    // fold odd half into even half (same cols in lanes i and i+32); den likewise
    ax  += __shfl_xor(ax, 32, 64);
    ay  += __shfl_xor(ay, 32, 64);
    az  += __shfl_xor(az, 32, 64);
    aw  += __shfl_xor(aw, 32, 64);
    den += __shfl_xor(den, 32, 64);

    if (half == 0) {
        float iv = 1.f / den;
        float4 b4 = *(const float4*)&bias[cq];
        float vx = ax * iv + b4.x;
        float vy = ay * iv + b4.y;
        float vz = az * iv + b4.z;
        float vw = aw * iv + b4.w;
        if (ACT) {
            vx = 2.f * tanhf(vx);
            vy = 2.f * tanhf(vy);
            vz = 2.f * tanhf(vz);
            vw = 2.f * tanhf(vw);
        }
        *(float4*)&out[(size_t)node * D + cq] = make_float4(vx, vy, vz, vw);
    }
}

// ---------------- launch ----------------

extern "C" void kernel_launch(void* const* d_in, const int* in_sizes, int n_in,
                              void* d_out, int out_size, void* d_ws, size_t ws_size,
                              hipStream_t stream) {
    const int N = in_sizes[0] / D;
    const int E = in_sizes[1] / 2;
    const float* x = (const float*)d_in[0];
    const int* ei = (const int*)d_in[1];
    const float* Wm[3] = {(const float*)d_in[2], (const float*)d_in[6], (const float*)d_in[10]};
    const float* aS[3] = {(const float*)d_in[3], (const float*)d_in[7], (const float*)d_in[11]};
    const float* aD[3] = {(const float*)d_in[4], (const float*)d_in[8], (const float*)d_in[12]};
    const float* bb[3] = {(const float*)d_in[5], (const float*)d_in[9], (const float*)d_in[13]};

    char* ws = (char*)d_ws;
    size_t off = 0;
    auto alloc = [&](size_t bytes) -> void* {
        void* p = ws + off;
        off = (off + bytes + 511) & ~(size_t)511;
        return p;
    };
    float* bufA  = (float*)alloc((size_t)N * D * 4);
    float* bufB  = (float*)alloc((size_t)N * D * 4);
    float* sArr  = (float*)alloc((size_t)N * 4);
    float* dArr  = (float*)alloc((size_t)N * 4);
    int*   deg   = (int*)alloc((size_t)N * 4);
    int*   rowptr= (int*)alloc((size_t)(N + 1) * 4);
    int*   tmp   = (int*)alloc((size_t)N * 4);
    int*   bsum  = (int*)alloc(256 * 4);
    int*   csr   = (int*)alloc((size_t)(E + N) * 4);
    (void)ws_size; (void)n_in; (void)out_size;

    const int B1 = (N + 255) / 256;

    k_init_deg<<<B1, 256, 0, stream>>>(deg, N);
    k_count<<<1024, 256, 0, stream>>>(ei, E, N, deg);
    k_scan1<<<B1, 256, 0, stream>>>(deg, N, tmp, bsum);
    k_scan2<<<1, 256, 0, stream>>>(bsum, B1);
    k_scan3<<<B1, 256, 0, stream>>>(tmp, bsum, N, E + N, rowptr, deg);
    k_fill<<<1024, 256, 0, stream>>>(ei, E, N, deg, csr);

    for (int l = 0; l < 3; l++) {
        if (l == 0) {
            k_gemm<true><<<(N + 31) / 32, 256, 0, stream>>>(x, Wm[0], aS[0], aD[0],
                                                            bufB, sArr, dArr, N);
        } else {
            k_gemm<false><<<(N + 31) / 32, 256, 0, stream>>>(bufA, Wm[l], aS[l], aD[l],
                                                             bufB, sArr, dArr, N);
        }
        if (l < 2) {
            k_agg<true><<<(N + 3) / 4, 256, 0, stream>>>(bufB, sArr, dArr, rowptr, csr,
                                                         bb[l], bufA, N);
        } else {
            k_agg<false><<<(N + 3) / 4, 256, 0, stream>>>(bufB, sArr, dArr, rowptr, csr,
                                                          bb[l], (float*)d_out, N);
        }
    }
}

// Round 7
// 638.716 us; speedup vs baseline: 2.3615x; 1.1838x over previous
//
#include <hip/hip_runtime.h>
#include <math.h>

#define D 128

typedef __attribute__((ext_vector_type(8))) short short8;
typedef __attribute__((ext_vector_type(4))) float float4v;

__device__ __forceinline__ unsigned short f2bf(float x) {
    unsigned u = __float_as_uint(x);
    u += ((u >> 16) & 1u) + 0x7fffu;          // RNE
    return (unsigned short)(u >> 16);
}
__device__ __forceinline__ float bf2f(unsigned short h) {
    return __uint_as_float((unsigned)h << 16);
}

// ---------------- CSR build (XCD-partitioned: blockIdx%8 -> dst range) ----------------

__global__ void k_init_deg(int* deg, int N) {
    int i = blockIdx.x * blockDim.x + threadIdx.x;
    if (i < N) deg[i] = 1;   // self-loop pre-counted
}

__global__ void k_count(const int* __restrict__ ei, int E, int N, int* deg) {
    int part = blockIdx.x & 7;
    int slice = blockIdx.x >> 3;
    int nsl = gridDim.x >> 3;
    int lo = (int)((long long)N * part >> 3);
    int hi = (int)((long long)N * (part + 1) >> 3);
    const int* dst = ei + E;
    for (int i = slice * blockDim.x + threadIdx.x; i < E; i += nsl * blockDim.x) {
        int d = dst[i];
        if (d >= lo && d < hi) atomicAdd(&deg[d], 1);
    }
}

__global__ void k_scan1(const int* __restrict__ deg, int N, int* tmp, int* bsum) {
    __shared__ int sh[256];
    int t = threadIdx.x;
    int i = blockIdx.x * 256 + t;
    int v = (i < N) ? deg[i] : 0;
    sh[t] = v;
    __syncthreads();
    for (int o = 1; o < 256; o <<= 1) {
        int u = (t >= o) ? sh[t - o] : 0;
        __syncthreads();
        sh[t] += u;
        __syncthreads();
    }
    if (i < N) tmp[i] = sh[t] - v;          // exclusive
    if (t == 255) bsum[blockIdx.x] = sh[255];
}

__global__ void k_scan2(int* bsum, int B) {
    __shared__ int sh[256];
    int t = threadIdx.x;
    int v = (t < B) ? bsum[t] : 0;
    sh[t] = v;
    __syncthreads();
    for (int o = 1; o < 256; o <<= 1) {
        int u = (t >= o) ? sh[t - o] : 0;
        __syncthreads();
        sh[t] += u;
        __syncthreads();
    }
    bsum[t] = sh[t] - v;
}

__global__ void k_scan3(const int* __restrict__ tmp, const int* __restrict__ bscan,
                        int N, int total, int* rowptr, int* fill) {
    int i = blockIdx.x * blockDim.x + threadIdx.x;
    if (i < N) {
        int r = tmp[i] + bscan[i >> 8];
        rowptr[i] = r;
        fill[i] = r;
    }
    if (i == 0) rowptr[N] = total;
}

__global__ void k_fill(const int* __restrict__ ei, int E, int N, int* fill, int* csr) {
    int part = blockIdx.x & 7;
    int slice = blockIdx.x >> 3;
    int nsl = gridDim.x >> 3;
    int lo = (int)((long long)N * part >> 3);
    int hi = (int)((long long)N * (part + 1) >> 3);
    int total = E + N;
    for (int i = slice * blockDim.x + threadIdx.x; i < total; i += nsl * blockDim.x) {
        int s_, d_;
        if (i < E) { s_ = ei[i]; d_ = ei[E + i]; }
        else       { s_ = d_ = i - E; }
        if (d_ >= lo && d_ < hi) {
            int p = atomicAdd(&fill[d_], 1);
            csr[p] = s_;
        }
    }
}

// ---------------- expmap0 ----------------

__global__ void k_expmap(const float* __restrict__ x, float* __restrict__ out, int N) {
    int lane = threadIdx.x & 63;
    int node = blockIdx.x * (blockDim.x >> 6) + (threadIdx.x >> 6);
    if (node >= N) return;
    float2 v = *(const float2*)&x[(size_t)node * D + 2 * lane];
    float ss = v.x * v.x + v.y * v.y;
    for (int o = 32; o; o >>= 1) ss += __shfl_xor(ss, o, 64);
    float n = sqrtf(ss);
    n = fmaxf(n, 1e-15f);
    float sc = tanhf(n) / n;
    *(float2*)&out[(size_t)node * D + 2 * lane] = make_float2(v.x * sc, v.y * sc);
}

// ---------------- W pack: fp32 [128,128] -> bf16 hi/lo in MFMA B-fragment order ------
// tile (ct,kt): lane holds W[k=kt*32+(lane>>4)*8+j][n=ct*16+(lane&15)], j=0..7
// memory: (((ct*4+kt)*64 + lane)*8 + j) shorts  -> per-lane 16B contiguous, coalesced.

__global__ void k_wpack(const float* __restrict__ W, unsigned short* __restrict__ whi,
                        unsigned short* __restrict__ wlo) {
    int id = blockIdx.x * blockDim.x + threadIdx.x;   // 0 .. 2047
    if (id >= 32 * 64) return;
    int lane = id & 63;
    int tile = id >> 6;          // ct*4 + kt
    int kt = tile & 3;
    int ct = tile >> 2;
    int k0 = kt * 32 + (lane >> 4) * 8;
    int n  = ct * 16 + (lane & 15);
    for (int j = 0; j < 8; j++) {
        float w = W[(k0 + j) * D + n];
        unsigned short h = f2bf(w);
        whi[(size_t)id * 8 + j] = h;
        wlo[(size_t)id * 8 + j] = f2bf(w - bf2f(h));
    }
}

// ---------------- MFMA GEMM (bf16x4 split = fp32 accuracy) + fused dots --------------
// 64 rows/block, 4 waves; wave w computes rows w*16..w*16+15 (all 128 cols).
// A staged in LDS as bf16 hi/lo, 16B blocks XOR-swizzled by row (2-way conflicts only).

__global__ __launch_bounds__(256) void k_gemm(const float* __restrict__ A,
                                              const unsigned short* __restrict__ Whi,
                                              const unsigned short* __restrict__ Wlo,
                                              const float* __restrict__ avS,
                                              const float* __restrict__ avD,
                                              float* __restrict__ H,
                                              float* __restrict__ sA,
                                              float* __restrict__ dA, int N) {
    __shared__ unsigned short AshHi[64 * D];   // 16 KB
    __shared__ unsigned short AshLo[64 * D];   // 16 KB
    int t = threadIdx.x;
    int row0 = blockIdx.x * 64;

    // stage 64x128 A as hi/lo bf16; task = (row_local, 16B-block)
    for (int i = 0; i < 4; i++) {
        int task = i * 256 + t;
        int rl = task >> 4;
        int bl = task & 15;
        int bp = bl ^ (rl & 15);               // swizzled block
        int rg = row0 + rl;
        float v[8];
        if (rg < N) {
            float4 x0 = *(const float4*)&A[(size_t)rg * D + bl * 8];
            float4 x1 = *(const float4*)&A[(size_t)rg * D + bl * 8 + 4];
            v[0] = x0.x; v[1] = x0.y; v[2] = x0.z; v[3] = x0.w;
            v[4] = x1.x; v[5] = x1.y; v[6] = x1.z; v[7] = x1.w;
        } else {
            for (int q = 0; q < 8; q++) v[q] = 0.f;
        }
        unsigned int ph[4], pl[4];
        for (int q = 0; q < 4; q++) {
            unsigned short h0 = f2bf(v[2 * q]), h1 = f2bf(v[2 * q + 1]);
            unsigned short l0 = f2bf(v[2 * q] - bf2f(h0));
            unsigned short l1 = f2bf(v[2 * q + 1] - bf2f(h1));
            ph[q] = (unsigned)h0 | ((unsigned)h1 << 16);
            pl[q] = (unsigned)l0 | ((unsigned)l1 << 16);
        }
        *(uint4*)&AshHi[rl * D + bp * 8] = make_uint4(ph[0], ph[1], ph[2], ph[3]);
        *(uint4*)&AshLo[rl * D + bp * 8] = make_uint4(pl[0], pl[1], pl[2], pl[3]);
    }
    __syncthreads();

    int wv = t >> 6, lane = t & 63, quad = lane >> 4, m = lane & 15;
    int rbase = wv * 16;
    float4v acc[8];
    for (int ct = 0; ct < 8; ct++) acc[ct] = (float4v){0.f, 0.f, 0.f, 0.f};

    for (int kt = 0; kt < 4; kt++) {
        int bp = (kt * 4 + quad) ^ m;
        short8 ahi = *(const short8*)&AshHi[(rbase + m) * D + bp * 8];
        short8 alo = *(const short8*)&AshLo[(rbase + m) * D + bp * 8];
#pragma unroll
        for (int ct = 0; ct < 8; ct++) {
            size_t wofs = ((size_t)((ct << 2) | kt) * 64 + lane) * 8;
            short8 whi = *(const short8*)&Whi[wofs];
            short8 wlo = *(const short8*)&Wlo[wofs];
            acc[ct] = __builtin_amdgcn_mfma_f32_16x16x32_bf16(alo, wlo, acc[ct], 0, 0, 0);
            acc[ct] = __builtin_amdgcn_mfma_f32_16x16x32_bf16(alo, whi, acc[ct], 0, 0, 0);
            acc[ct] = __builtin_amdgcn_mfma_f32_16x16x32_bf16(ahi, wlo, acc[ct], 0, 0, 0);
            acc[ct] = __builtin_amdgcn_mfma_f32_16x16x32_bf16(ahi, whi, acc[ct], 0, 0, 0);
        }
    }

    // store H (C/D layout: col=m, row=quad*4+r)
    int growbase = row0 + rbase + quad * 4;
    for (int r = 0; r < 4; r++) {
        int gr = growbase + r;
        if (gr < N) {
#pragma unroll
            for (int ct = 0; ct < 8; ct++)
                H[(size_t)gr * D + ct * 16 + m] = acc[ct][r];
        }
    }

    // fused dots: reduce over the 16 lanes of each quad
    float ps[4] = {0, 0, 0, 0}, pd[4] = {0, 0, 0, 0};
#pragma unroll
    for (int ct = 0; ct < 8; ct++) {
        float as_v = avS[ct * 16 + m];
        float ad_v = avD[ct * 16 + m];
        for (int r = 0; r < 4; r++) {
            ps[r] += acc[ct][r] * as_v;
            pd[r] += acc[ct][r] * ad_v;
        }
    }
    for (int o = 1; o < 16; o <<= 1) {
        for (int r = 0; r < 4; r++) {
            ps[r] += __shfl_xor(ps[r], o, 64);
            pd[r] += __shfl_xor(pd[r], o, 64);
        }
    }
    if (m == 0) {
        for (int r = 0; r < 4; r++) {
            int gr = growbase + r;
            if (gr < N) { sA[gr] = ps[r]; dA[gr] = pd[r]; }
        }
    }
}

// ---------------- fused softmax + aggregation: one wave per dst ----------------------

template <bool ACT>
__global__ __launch_bounds__(256) void k_agg(const float* __restrict__ H,
                                             const float* __restrict__ sA,
                                             const float* __restrict__ dA,
                                             const int* __restrict__ rowptr,
                                             const int* __restrict__ csr,
                                             const float* __restrict__ bias,
                                             float* __restrict__ out, int N) {
    int lane = threadIdx.x & 63;
    int node = blockIdx.x * 4 + (threadIdx.x >> 6);
    if (node >= N) return;
    int start = __builtin_amdgcn_readfirstlane(rowptr[node]);
    int end   = __builtin_amdgcn_readfirstlane(rowptr[node + 1]);
    float di  = dA[node];
    int half  = lane >> 5;
    int cq    = (lane & 31) * 4;

    float ax = 0.f, ay = 0.f, az = 0.f, aw = 0.f;
    float den = 0.f;
    int j = start;
    for (; j + 4 <= end; j += 4) {
        int s0 = csr[j + 0], s1 = csr[j + 1], s2 = csr[j + 2], s3 = csr[j + 3];
        float e0 = sA[s0] + di, e1 = sA[s1] + di, e2 = sA[s2] + di, e3 = sA[s3] + di;
        e0 = (e0 > 0.f) ? e0 : 0.2f * e0;
        e1 = (e1 > 0.f) ? e1 : 0.2f * e1;
        e2 = (e2 > 0.f) ? e2 : 0.2f * e2;
        e3 = (e3 > 0.f) ? e3 : 0.2f * e3;
        float p0 = __expf(e0), p1 = __expf(e1), p2 = __expf(e2), p3 = __expf(e3);
        int   sa = half ? s1 : s0;
        int   sb = half ? s3 : s2;
        float wa = half ? p1 : p0;
        float wb = half ? p3 : p2;
        den += wa + wb;
        float4 ha = *(const float4*)&H[(size_t)sa * D + cq];
        float4 hb = *(const float4*)&H[(size_t)sb * D + cq];
        ax += wa * ha.x + wb * hb.x;
        ay += wa * ha.y + wb * hb.y;
        az += wa * ha.z + wb * hb.z;
        aw += wa * ha.w + wb * hb.w;
    }
    if (j + 2 <= end) {
        int s0 = csr[j + 0], s1 = csr[j + 1];
        float e0 = sA[s0] + di, e1 = sA[s1] + di;
        e0 = (e0 > 0.f) ? e0 : 0.2f * e0;
        e1 = (e1 > 0.f) ? e1 : 0.2f * e1;
        float p0 = __expf(e0), p1 = __expf(e1);
        int   sa = half ? s1 : s0;
        float wa = half ? p1 : p0;
        den += wa;
        float4 ha = *(const float4*)&H[(size_t)sa * D + cq];
        ax += wa * ha.x; ay += wa * ha.y; az += wa * ha.z; aw += wa * ha.w;
        j += 2;
    }
    if (j < end && half == 0) {
        int s0 = csr[j];
        float e0 = sA[s0] + di;
        e0 = (e0 > 0.f) ? e0 : 0.2f * e0;
        float p0 = __expf(e0);
        den += p0;
        float4 ha = *(const float4*)&H[(size_t)s0 * D + cq];
        ax += p0 * ha.x; ay += p0 * ha.y; az += p0 * ha.z; aw += p0 * ha.w;
    }

    ax  += __shfl_xor(ax, 32, 64);
    ay  += __shfl_xor(ay, 32, 64);
    az  += __shfl_xor(az, 32, 64);
    aw  += __shfl_xor(aw, 32, 64);
    den += __shfl_xor(den, 32, 64);

    if (half == 0) {
        float iv = 1.f / den;
        float4 b4 = *(const float4*)&bias[cq];
        float vx = ax * iv + b4.x;
        float vy = ay * iv + b4.y;
        float vz = az * iv + b4.z;
        float vw = aw * iv + b4.w;
        if (ACT) {
            vx = 2.f * tanhf(vx);
            vy = 2.f * tanhf(vy);
            vz = 2.f * tanhf(vz);
            vw = 2.f * tanhf(vw);
        }
        *(float4*)&out[(size_t)node * D + cq] = make_float4(vx, vy, vz, vw);
    }
}

// ---------------- launch ----------------

extern "C" void kernel_launch(void* const* d_in, const int* in_sizes, int n_in,
                              void* d_out, int out_size, void* d_ws, size_t ws_size,
                              hipStream_t stream) {
    const int N = in_sizes[0] / D;
    const int E = in_sizes[1] / 2;
    const float* x = (const float*)d_in[0];
    const int* ei = (const int*)d_in[1];
    const float* Wm[3] = {(const float*)d_in[2], (const float*)d_in[6], (const float*)d_in[10]};
    const float* aS[3] = {(const float*)d_in[3], (const float*)d_in[7], (const float*)d_in[11]};
    const float* aD[3] = {(const float*)d_in[4], (const float*)d_in[8], (const float*)d_in[12]};
    const float* bb[3] = {(const float*)d_in[5], (const float*)d_in[9], (const float*)d_in[13]};

    char* ws = (char*)d_ws;
    size_t off = 0;
    auto alloc = [&](size_t bytes) -> void* {
        void* p = ws + off;
        off = (off + bytes + 511) & ~(size_t)511;
        return p;
    };
    float* bufA  = (float*)alloc((size_t)N * D * 4);
    float* bufB  = (float*)alloc((size_t)N * D * 4);
    float* sArr  = (float*)alloc((size_t)N * 4);
    float* dArr  = (float*)alloc((size_t)N * 4);
    int*   deg   = (int*)alloc((size_t)N * 4);
    int*   rowptr= (int*)alloc((size_t)(N + 1) * 4);
    int*   tmp   = (int*)alloc((size_t)N * 4);
    int*   bsum  = (int*)alloc(256 * 4);
    int*   csr   = (int*)alloc((size_t)(E + N) * 4);
    unsigned short* whi[3];
    unsigned short* wlo[3];
    for (int l = 0; l < 3; l++) {
        whi[l] = (unsigned short*)alloc((size_t)D * D * 2);
        wlo[l] = (unsigned short*)alloc((size_t)D * D * 2);
    }
    (void)ws_size; (void)n_in; (void)out_size;

    const int B1 = (N + 255) / 256;

    k_init_deg<<<B1, 256, 0, stream>>>(deg, N);
    k_count<<<1024, 256, 0, stream>>>(ei, E, N, deg);
    k_scan1<<<B1, 256, 0, stream>>>(deg, N, tmp, bsum);
    k_scan2<<<1, 256, 0, stream>>>(bsum, B1);
    k_scan3<<<B1, 256, 0, stream>>>(tmp, bsum, N, E + N, rowptr, deg);
    k_fill<<<1024, 256, 0, stream>>>(ei, E, N, deg, csr);

    for (int l = 0; l < 3; l++)
        k_wpack<<<8, 256, 0, stream>>>(Wm[l], whi[l], wlo[l]);

    k_expmap<<<(N + 3) / 4, 256, 0, stream>>>(x, bufA, N);

    const int gemmBlocks = (N + 63) / 64;
    for (int l = 0; l < 3; l++) {
        k_gemm<<<gemmBlocks, 256, 0, stream>>>(bufA, whi[l], wlo[l], aS[l], aD[l],
                                               bufB, sArr, dArr, N);
        if (l < 2) {
            k_agg<true><<<(N + 3) / 4, 256, 0, stream>>>(bufB, sArr, dArr, rowptr, csr,
                                                         bb[l], bufA, N);
        } else {
            k_agg<false><<<(N + 3) / 4, 256, 0, stream>>>(bufB, sArr, dArr, rowptr, csr,
                                                          bb[l], (float*)d_out, N);
        }
    }
}

// Round 8
// 625.763 us; speedup vs baseline: 2.4104x; 1.0207x over previous
//
#include <hip/hip_runtime.h>
#include <math.h>

#define D 128

typedef __attribute__((ext_vector_type(8))) short short8;
typedef __attribute__((ext_vector_type(4))) float float4v;

__device__ __forceinline__ unsigned short f2bf(float x) {
    unsigned u = __float_as_uint(x);
    u += ((u >> 16) & 1u) + 0x7fffu;          // RNE
    return (unsigned short)(u >> 16);
}
__device__ __forceinline__ float bf2f(unsigned short h) {
    return __uint_as_float((unsigned)h << 16);
}

// ---------------- CSR build (XCD-partitioned: blockIdx%8 -> dst range) ----------------

__global__ void k_init_deg(int* deg, int N) {
    int i = blockIdx.x * blockDim.x + threadIdx.x;
    if (i < N) deg[i] = 1;   // self-loop pre-counted
}

__global__ void k_count(const int* __restrict__ ei, int E, int N, int* deg) {
    int part = blockIdx.x & 7;
    int slice = blockIdx.x >> 3;
    int nsl = gridDim.x >> 3;
    int lo = (int)((long long)N * part >> 3);
    int hi = (int)((long long)N * (part + 1) >> 3);
    const int* dst = ei + E;
    for (int i = slice * blockDim.x + threadIdx.x; i < E; i += nsl * blockDim.x) {
        int d = dst[i];
        if (d >= lo && d < hi) atomicAdd(&deg[d], 1);
    }
}

__global__ void k_scan1(const int* __restrict__ deg, int N, int* tmp, int* bsum) {
    __shared__ int sh[256];
    int t = threadIdx.x;
    int i = blockIdx.x * 256 + t;
    int v = (i < N) ? deg[i] : 0;
    sh[t] = v;
    __syncthreads();
    for (int o = 1; o < 256; o <<= 1) {
        int u = (t >= o) ? sh[t - o] : 0;
        __syncthreads();
        sh[t] += u;
        __syncthreads();
    }
    if (i < N) tmp[i] = sh[t] - v;          // exclusive
    if (t == 255) bsum[blockIdx.x] = sh[255];
}

__global__ void k_scan2(int* bsum, int B) {
    __shared__ int sh[256];
    int t = threadIdx.x;
    int v = (t < B) ? bsum[t] : 0;
    sh[t] = v;
    __syncthreads();
    for (int o = 1; o < 256; o <<= 1) {
        int u = (t >= o) ? sh[t - o] : 0;
        __syncthreads();
        sh[t] += u;
        __syncthreads();
    }
    bsum[t] = sh[t] - v;
}

__global__ void k_scan3(const int* __restrict__ tmp, const int* __restrict__ bscan,
                        int N, int total, int* rowptr, int* fill) {
    int i = blockIdx.x * blockDim.x + threadIdx.x;
    if (i < N) {
        int r = tmp[i] + bscan[i >> 8];
        rowptr[i] = r;
        fill[i] = r;
    }
    if (i == 0) rowptr[N] = total;
}

__global__ void k_fill(const int* __restrict__ ei, int E, int N, int* fill, int* csr) {
    int part = blockIdx.x & 7;
    int slice = blockIdx.x >> 3;
    int nsl = gridDim.x >> 3;
    int lo = (int)((long long)N * part >> 3);
    int hi = (int)((long long)N * (part + 1) >> 3);
    int total = E + N;
    const int* dst = ei + E;
    for (int i = slice * blockDim.x + threadIdx.x; i < total; i += nsl * blockDim.x) {
        int d_ = (i < E) ? dst[i] : i - E;
        if (d_ >= lo && d_ < hi) {
            int s_ = (i < E) ? ei[i] : i - E;    // src read only when in-partition
            int p = atomicAdd(&fill[d_], 1);
            csr[p] = s_;
        }
    }
}

// ---------------- W pack (all 3 layers, one launch): fp32 -> bf16 hi/lo fragments ----
// tile (ct,kt): lane holds W[k=kt*32+(lane>>4)*8+j][n=ct*16+(lane&15)], j=0..7

__global__ void k_wpack3(const float* __restrict__ W0, const float* __restrict__ W1,
                         const float* __restrict__ W2, unsigned short* __restrict__ whi,
                         unsigned short* __restrict__ wlo) {
    int id = blockIdx.x * blockDim.x + threadIdx.x;   // 0 .. 6143
    int l = id >> 11;
    int id2 = id & 2047;
    const float* W = (l == 0) ? W0 : (l == 1) ? W1 : W2;
    int lane = id2 & 63;
    int tile = id2 >> 6;          // ct*4 + kt
    int kt = tile & 3;
    int ct = tile >> 2;
    int k0 = kt * 32 + (lane >> 4) * 8;
    int n  = ct * 16 + (lane & 15);
    size_t base = (size_t)l * 16384 + (size_t)id2 * 8;
    for (int j = 0; j < 8; j++) {
        float w = W[(k0 + j) * D + n];
        unsigned short h = f2bf(w);
        whi[base + j] = h;
        wlo[base + j] = f2bf(w - bf2f(h));
    }
}

// ---------------- MFMA GEMM, LDS-free (bf16x4 split = fp32 accuracy) + fused dots ----
// Wave = 16 rows x 128 cols. A fragments loaded straight from row-major global
// (per lane: 2 dwordx4 per kt -> wave covers 16 rows x 128B contiguous).
// EXP: fused expmap0 (lanes m,m+16,m+32,m+48 hold row m's 4 k-slices -> 2 shuffles).

template <bool EXP>
__global__ __launch_bounds__(256) void k_gemm(const float* __restrict__ A,
                                              const unsigned short* __restrict__ Whi,
                                              const unsigned short* __restrict__ Wlo,
                                              const float* __restrict__ avS,
                                              const float* __restrict__ avD,
                                              float* __restrict__ H,
                                              float* __restrict__ sA,
                                              float* __restrict__ dA, int N) {
    int t = threadIdx.x;
    int wv = t >> 6, lane = t & 63, quad = lane >> 4, m = lane & 15;
    int rg = blockIdx.x * 64 + wv * 16 + m;          // this lane's A row
    bool valid = rg < N;
    const float* arow = &A[(size_t)(valid ? rg : 0) * D];

    float af[32];
#pragma unroll
    for (int kt = 0; kt < 4; kt++) {
        int k0 = kt * 32 + quad * 8;
        float4 x0 = valid ? *(const float4*)&arow[k0]     : make_float4(0.f, 0.f, 0.f, 0.f);
        float4 x1 = valid ? *(const float4*)&arow[k0 + 4] : make_float4(0.f, 0.f, 0.f, 0.f);
        af[kt * 8 + 0] = x0.x; af[kt * 8 + 1] = x0.y; af[kt * 8 + 2] = x0.z; af[kt * 8 + 3] = x0.w;
        af[kt * 8 + 4] = x1.x; af[kt * 8 + 5] = x1.y; af[kt * 8 + 6] = x1.z; af[kt * 8 + 7] = x1.w;
    }

    if (EXP) {
        float ss = 0.f;
#pragma unroll
        for (int q = 0; q < 32; q++) ss += af[q] * af[q];
        ss += __shfl_xor(ss, 16, 64);
        ss += __shfl_xor(ss, 32, 64);
        float n = fmaxf(sqrtf(ss), 1e-15f);
        float sc = tanhf(n) / n;
#pragma unroll
        for (int q = 0; q < 32; q++) af[q] *= sc;
    }

    short8 ahi[4], alo[4];
#pragma unroll
    for (int kt = 0; kt < 4; kt++) {
#pragma unroll
        for (int j = 0; j < 8; j++) {
            float v = af[kt * 8 + j];
            unsigned short h = f2bf(v);
            ahi[kt][j] = (short)h;
            alo[kt][j] = (short)f2bf(v - bf2f(h));
        }
    }

    float4v acc[8];
#pragma unroll
    for (int ct = 0; ct < 8; ct++) acc[ct] = (float4v){0.f, 0.f, 0.f, 0.f};

#pragma unroll
    for (int kt = 0; kt < 4; kt++) {
#pragma unroll
        for (int ct = 0; ct < 8; ct++) {
            size_t wofs = ((size_t)((ct << 2) | kt) * 64 + lane) * 8;
            short8 whi = *(const short8*)&Whi[wofs];
            short8 wlo = *(const short8*)&Wlo[wofs];
            acc[ct] = __builtin_amdgcn_mfma_f32_16x16x32_bf16(alo[kt], wlo, acc[ct], 0, 0, 0);
            acc[ct] = __builtin_amdgcn_mfma_f32_16x16x32_bf16(alo[kt], whi, acc[ct], 0, 0, 0);
            acc[ct] = __builtin_amdgcn_mfma_f32_16x16x32_bf16(ahi[kt], wlo, acc[ct], 0, 0, 0);
            acc[ct] = __builtin_amdgcn_mfma_f32_16x16x32_bf16(ahi[kt], whi, acc[ct], 0, 0, 0);
        }
    }

    // store H (C/D layout: col=m, row=quad*4+r)
    int growbase = blockIdx.x * 64 + wv * 16 + quad * 4;
#pragma unroll
    for (int r = 0; r < 4; r++) {
        int gr = growbase + r;
        if (gr < N) {
#pragma unroll
            for (int ct = 0; ct < 8; ct++)
                H[(size_t)gr * D + ct * 16 + m] = acc[ct][r];
        }
    }

    // fused dots: reduce over the 16 lanes of each quad
    float ps[4] = {0, 0, 0, 0}, pd[4] = {0, 0, 0, 0};
#pragma unroll
    for (int ct = 0; ct < 8; ct++) {
        float as_v = avS[ct * 16 + m];
        float ad_v = avD[ct * 16 + m];
#pragma unroll
        for (int r = 0; r < 4; r++) {
            ps[r] += acc[ct][r] * as_v;
            pd[r] += acc[ct][r] * ad_v;
        }
    }
    for (int o = 1; o < 16; o <<= 1) {
#pragma unroll
        for (int r = 0; r < 4; r++) {
            ps[r] += __shfl_xor(ps[r], o, 64);
            pd[r] += __shfl_xor(pd[r], o, 64);
        }
    }
    if (m == 0) {
#pragma unroll
        for (int r = 0; r < 4; r++) {
            int gr = growbase + r;
            if (gr < N) { sA[gr] = ps[r]; dA[gr] = pd[r]; }
        }
    }
}

// ---------------- fused softmax + aggregation: one wave per dst ----------------------

template <bool ACT>
__global__ __launch_bounds__(256) void k_agg(const float* __restrict__ H,
                                             const float* __restrict__ sA,
                                             const float* __restrict__ dA,
                                             const int* __restrict__ rowptr,
                                             const int* __restrict__ csr,
                                             const float* __restrict__ bias,
                                             float* __restrict__ out, int N) {
    int lane = threadIdx.x & 63;
    int node = blockIdx.x * 4 + (threadIdx.x >> 6);
    if (node >= N) return;
    int start = __builtin_amdgcn_readfirstlane(rowptr[node]);
    int end   = __builtin_amdgcn_readfirstlane(rowptr[node + 1]);
    float di  = dA[node];
    int half  = lane >> 5;
    int cq    = (lane & 31) * 4;

    float ax = 0.f, ay = 0.f, az = 0.f, aw = 0.f;
    float den = 0.f;
    int j = start;
    for (; j + 4 <= end; j += 4) {
        int s0 = csr[j + 0], s1 = csr[j + 1], s2 = csr[j + 2], s3 = csr[j + 3];
        float e0 = sA[s0] + di, e1 = sA[s1] + di, e2 = sA[s2] + di, e3 = sA[s3] + di;
        e0 = (e0 > 0.f) ? e0 : 0.2f * e0;
        e1 = (e1 > 0.f) ? e1 : 0.2f * e1;
        e2 = (e2 > 0.f) ? e2 : 0.2f * e2;
        e3 = (e3 > 0.f) ? e3 : 0.2f * e3;
        float p0 = __expf(e0), p1 = __expf(e1), p2 = __expf(e2), p3 = __expf(e3);
        int   sa = half ? s1 : s0;
        int   sb = half ? s3 : s2;
        float wa = half ? p1 : p0;
        float wb = half ? p3 : p2;
        den += wa + wb;
        float4 ha = *(const float4*)&H[(size_t)sa * D + cq];
        float4 hb = *(const float4*)&H[(size_t)sb * D + cq];
        ax += wa * ha.x + wb * hb.x;
        ay += wa * ha.y + wb * hb.y;
        az += wa * ha.z + wb * hb.z;
        aw += wa * ha.w + wb * hb.w;
    }
    if (j + 2 <= end) {
        int s0 = csr[j + 0], s1 = csr[j + 1];
        float e0 = sA[s0] + di, e1 = sA[s1] + di;
        e0 = (e0 > 0.f) ? e0 : 0.2f * e0;
        e1 = (e1 > 0.f) ? e1 : 0.2f * e1;
        float p0 = __expf(e0), p1 = __expf(e1);
        int   sa = half ? s1 : s0;
        float wa = half ? p1 : p0;
        den += wa;
        float4 ha = *(const float4*)&H[(size_t)sa * D + cq];
        ax += wa * ha.x; ay += wa * ha.y; az += wa * ha.z; aw += wa * ha.w;
        j += 2;
    }
    if (j < end && half == 0) {
        int s0 = csr[j];
        float e0 = sA[s0] + di;
        e0 = (e0 > 0.f) ? e0 : 0.2f * e0;
        float p0 = __expf(e0);
        den += p0;
        float4 ha = *(const float4*)&H[(size_t)s0 * D + cq];
        ax += p0 * ha.x; ay += p0 * ha.y; az += p0 * ha.z; aw += p0 * ha.w;
    }

    ax  += __shfl_xor(ax, 32, 64);
    ay  += __shfl_xor(ay, 32, 64);
    az  += __shfl_xor(az, 32, 64);
    aw  += __shfl_xor(aw, 32, 64);
    den += __shfl_xor(den, 32, 64);

    if (half == 0) {
        float iv = 1.f / den;
        float4 b4 = *(const float4*)&bias[cq];
        float vx = ax * iv + b4.x;
        float vy = ay * iv + b4.y;
        float vz = az * iv + b4.z;
        float vw = aw * iv + b4.w;
        if (ACT) {
            vx = 2.f * tanhf(vx);
            vy = 2.f * tanhf(vy);
            vz = 2.f * tanhf(vz);
            vw = 2.f * tanhf(vw);
        }
        *(float4*)&out[(size_t)node * D + cq] = make_float4(vx, vy, vz, vw);
    }
}

// ---------------- launch ----------------

extern "C" void kernel_launch(void* const* d_in, const int* in_sizes, int n_in,
                              void* d_out, int out_size, void* d_ws, size_t ws_size,
                              hipStream_t stream) {
    const int N = in_sizes[0] / D;
    const int E = in_sizes[1] / 2;
    const float* x = (const float*)d_in[0];
    const int* ei = (const int*)d_in[1];
    const float* Wm[3] = {(const float*)d_in[2], (const float*)d_in[6], (const float*)d_in[10]};
    const float* aS[3] = {(const float*)d_in[3], (const float*)d_in[7], (const float*)d_in[11]};
    const float* aD[3] = {(const float*)d_in[4], (const float*)d_in[8], (const float*)d_in[12]};
    const float* bb[3] = {(const float*)d_in[5], (const float*)d_in[9], (const float*)d_in[13]};

    char* ws = (char*)d_ws;
    size_t off = 0;
    auto alloc = [&](size_t bytes) -> void* {
        void* p = ws + off;
        off = (off + bytes + 511) & ~(size_t)511;
        return p;
    };
    float* bufA  = (float*)alloc((size_t)N * D * 4);
    float* bufB  = (float*)alloc((size_t)N * D * 4);
    float* sArr  = (float*)alloc((size_t)N * 4);
    float* dArr  = (float*)alloc((size_t)N * 4);
    int*   deg   = (int*)alloc((size_t)N * 4);
    int*   rowptr= (int*)alloc((size_t)(N + 1) * 4);
    int*   tmp   = (int*)alloc((size_t)N * 4);
    int*   bsum  = (int*)alloc(256 * 4);
    int*   csr   = (int*)alloc((size_t)(E + N) * 4);
    unsigned short* whiB = (unsigned short*)alloc((size_t)3 * D * D * 2);
    unsigned short* wloB = (unsigned short*)alloc((size_t)3 * D * D * 2);
    (void)ws_size; (void)n_in; (void)out_size;

    const int B1 = (N + 255) / 256;

    k_init_deg<<<B1, 256, 0, stream>>>(deg, N);
    k_count<<<1024, 256, 0, stream>>>(ei, E, N, deg);
    k_scan1<<<B1, 256, 0, stream>>>(deg, N, tmp, bsum);
    k_scan2<<<1, 256, 0, stream>>>(bsum, B1);
    k_scan3<<<B1, 256, 0, stream>>>(tmp, bsum, N, E + N, rowptr, deg);
    k_fill<<<1024, 256, 0, stream>>>(ei, E, N, deg, csr);

    k_wpack3<<<24, 256, 0, stream>>>(Wm[0], Wm[1], Wm[2], whiB, wloB);

    const int gemmBlocks = (N + 63) / 64;
    for (int l = 0; l < 3; l++) {
        const unsigned short* whi = whiB + (size_t)l * 16384;
        const unsigned short* wlo = wloB + (size_t)l * 16384;
        if (l == 0) {
            k_gemm<true><<<gemmBlocks, 256, 0, stream>>>(x, whi, wlo, aS[0], aD[0],
                                                         bufB, sArr, dArr, N);
        } else {
            k_gemm<false><<<gemmBlocks, 256, 0, stream>>>(bufA, whi, wlo, aS[l], aD[l],
                                                          bufB, sArr, dArr, N);
        }
        if (l < 2) {
            k_agg<true><<<(N + 3) / 4, 256, 0, stream>>>(bufB, sArr, dArr, rowptr, csr,
                                                         bb[l], bufA, N);
        } else {
            k_agg<false><<<(N + 3) / 4, 256, 0, stream>>>(bufB, sArr, dArr, rowptr, csr,
                                                          bb[l], (float*)d_out, N);
        }
    }
}

// Round 9
// 618.887 us; speedup vs baseline: 2.4372x; 1.0111x over previous
//
#include <hip/hip_runtime.h>
#include <math.h>

#define D 128

typedef __attribute__((ext_vector_type(8))) short short8;
typedef __attribute__((ext_vector_type(4))) float float4v;

__device__ __forceinline__ unsigned short f2bf(float x) {
    unsigned u = __float_as_uint(x);
    u += ((u >> 16) & 1u) + 0x7fffu;          // RNE
    return (unsigned short)(u >> 16);
}
__device__ __forceinline__ float bf2f(unsigned short h) {
    return __uint_as_float((unsigned)h << 16);
}

// ---------------- CSR build (XCD-partitioned: blockIdx%8 -> dst range) ----------------

__global__ void k_init_deg(int* deg, int N) {
    int i = blockIdx.x * blockDim.x + threadIdx.x;
    if (i < N) deg[i] = 1;   // self-loop pre-counted
}

__global__ void k_count(const int* __restrict__ ei, int E, int N, int* deg) {
    int part = blockIdx.x & 7;
    int slice = blockIdx.x >> 3;
    int nsl = gridDim.x >> 3;
    int lo = (int)((long long)N * part >> 3);
    int hi = (int)((long long)N * (part + 1) >> 3);
    const int* dst = ei + E;
    for (int i = slice * blockDim.x + threadIdx.x; i < E; i += nsl * blockDim.x) {
        int d = dst[i];
        if (d >= lo && d < hi) atomicAdd(&deg[d], 1);
    }
}

__global__ void k_scan1(const int* __restrict__ deg, int N, int* tmp, int* bsum) {
    __shared__ int sh[256];
    int t = threadIdx.x;
    int i = blockIdx.x * 256 + t;
    int v = (i < N) ? deg[i] : 0;
    sh[t] = v;
    __syncthreads();
    for (int o = 1; o < 256; o <<= 1) {
        int u = (t >= o) ? sh[t - o] : 0;
        __syncthreads();
        sh[t] += u;
        __syncthreads();
    }
    if (i < N) tmp[i] = sh[t] - v;          // exclusive
    if (t == 255) bsum[blockIdx.x] = sh[255];
}

__global__ void k_scan2(int* bsum, int B) {
    __shared__ int sh[256];
    int t = threadIdx.x;
    int v = (t < B) ? bsum[t] : 0;
    sh[t] = v;
    __syncthreads();
    for (int o = 1; o < 256; o <<= 1) {
        int u = (t >= o) ? sh[t - o] : 0;
        __syncthreads();
        sh[t] += u;
        __syncthreads();
    }
    bsum[t] = sh[t] - v;
}

__global__ void k_scan3(const int* __restrict__ tmp, const int* __restrict__ bscan,
                        int N, int total, int* rowptr, int* fill) {
    int i = blockIdx.x * blockDim.x + threadIdx.x;
    if (i < N) {
        int r = tmp[i] + bscan[i >> 8];
        rowptr[i] = r;
        fill[i] = r;
    }
    if (i == 0) rowptr[N] = total;
}

__global__ void k_fill(const int* __restrict__ ei, int E, int N, int* fill, int* csr) {
    int part = blockIdx.x & 7;
    int slice = blockIdx.x >> 3;
    int nsl = gridDim.x >> 3;
    int lo = (int)((long long)N * part >> 3);
    int hi = (int)((long long)N * (part + 1) >> 3);
    int total = E + N;
    const int* dst = ei + E;
    for (int i = slice * blockDim.x + threadIdx.x; i < total; i += nsl * blockDim.x) {
        int d_ = (i < E) ? dst[i] : i - E;
        if (d_ >= lo && d_ < hi) {
            int s_ = (i < E) ? ei[i] : i - E;    // src read only when in-partition
            int p = atomicAdd(&fill[d_], 1);
            csr[p] = s_;
        }
    }
}

// ---------------- W pack (all 3 layers, one launch): fp32 -> bf16 hi/lo fragments ----
// tile (ct,kt): lane holds W[k=kt*32+(lane>>4)*8+j][n=ct*16+(lane&15)], j=0..7

__global__ void k_wpack3(const float* __restrict__ W0, const float* __restrict__ W1,
                         const float* __restrict__ W2, unsigned short* __restrict__ whi,
                         unsigned short* __restrict__ wlo) {
    int id = blockIdx.x * blockDim.x + threadIdx.x;   // 0 .. 6143
    int l = id >> 11;
    int id2 = id & 2047;
    const float* W = (l == 0) ? W0 : (l == 1) ? W1 : W2;
    int lane = id2 & 63;
    int tile = id2 >> 6;          // ct*4 + kt
    int kt = tile & 3;
    int ct = tile >> 2;
    int k0 = kt * 32 + (lane >> 4) * 8;
    int n  = ct * 16 + (lane & 15);
    size_t base = (size_t)l * 16384 + (size_t)id2 * 8;
    for (int j = 0; j < 8; j++) {
        float w = W[(k0 + j) * D + n];
        unsigned short h = f2bf(w);
        whi[base + j] = h;
        wlo[base + j] = f2bf(w - bf2f(h));
    }
}

// ---------------- MFMA GEMM: W hi/lo staged in LDS, A in registers -------------------
// bf16x4 split = fp32 accuracy. Wave = 16 rows x 128 cols; A fragments loaded straight
// from row-major global. W (64 KB) staged once per block -> ds_read_b128 inner loop
// (16B/lane = 2-way bank alias = free). EXP: fused expmap0 (2 shuffles/row).

template <bool EXP>
__global__ __launch_bounds__(256) void k_gemm(const float* __restrict__ A,
                                              const unsigned short* __restrict__ Whi,
                                              const unsigned short* __restrict__ Wlo,
                                              const float* __restrict__ avS,
                                              const float* __restrict__ avD,
                                              float* __restrict__ H,
                                              float* __restrict__ sA,
                                              float* __restrict__ dA, int N) {
    __shared__ unsigned short WshHi[16384];   // 32 KB
    __shared__ unsigned short WshLo[16384];   // 32 KB
    int t = threadIdx.x;
    int wv = t >> 6, lane = t & 63, quad = lane >> 4, m = lane & 15;

    // stage W hi/lo into LDS (linear copy, fully coalesced)
    {
        const uint4* gh = (const uint4*)Whi;
        const uint4* gl = (const uint4*)Wlo;
        uint4* sh = (uint4*)WshHi;
        uint4* sl = (uint4*)WshLo;
#pragma unroll
        for (int i = 0; i < 8; i++) {
            sh[i * 256 + t] = gh[i * 256 + t];
            sl[i * 256 + t] = gl[i * 256 + t];
        }
    }

    int rg = blockIdx.x * 64 + wv * 16 + m;          // this lane's A row
    bool valid = rg < N;
    const float* arow = &A[(size_t)(valid ? rg : 0) * D];

    float af[32];
#pragma unroll
    for (int kt = 0; kt < 4; kt++) {
        int k0 = kt * 32 + quad * 8;
        float4 x0 = valid ? *(const float4*)&arow[k0]     : make_float4(0.f, 0.f, 0.f, 0.f);
        float4 x1 = valid ? *(const float4*)&arow[k0 + 4] : make_float4(0.f, 0.f, 0.f, 0.f);
        af[kt * 8 + 0] = x0.x; af[kt * 8 + 1] = x0.y; af[kt * 8 + 2] = x0.z; af[kt * 8 + 3] = x0.w;
        af[kt * 8 + 4] = x1.x; af[kt * 8 + 5] = x1.y; af[kt * 8 + 6] = x1.z; af[kt * 8 + 7] = x1.w;
    }

    if (EXP) {
        float ss = 0.f;
#pragma unroll
        for (int q = 0; q < 32; q++) ss += af[q] * af[q];
        ss += __shfl_xor(ss, 16, 64);
        ss += __shfl_xor(ss, 32, 64);
        float n = fmaxf(sqrtf(ss), 1e-15f);
        float sc = tanhf(n) / n;
#pragma unroll
        for (int q = 0; q < 32; q++) af[q] *= sc;
    }

    short8 ahi[4], alo[4];
#pragma unroll
    for (int kt = 0; kt < 4; kt++) {
#pragma unroll
        for (int j = 0; j < 8; j++) {
            float v = af[kt * 8 + j];
            unsigned short h = f2bf(v);
            ahi[kt][j] = (short)h;
            alo[kt][j] = (short)f2bf(v - bf2f(h));
        }
    }

    __syncthreads();

    float4v acc[8];
#pragma unroll
    for (int ct = 0; ct < 8; ct++) acc[ct] = (float4v){0.f, 0.f, 0.f, 0.f};

#pragma unroll
    for (int kt = 0; kt < 4; kt++) {
#pragma unroll
        for (int ct = 0; ct < 8; ct++) {
            int wofs = (((ct << 2) | kt) * 64 + lane) * 8;
            short8 whi = *(const short8*)&WshHi[wofs];
            short8 wlo = *(const short8*)&WshLo[wofs];
            acc[ct] = __builtin_amdgcn_mfma_f32_16x16x32_bf16(alo[kt], wlo, acc[ct], 0, 0, 0);
            acc[ct] = __builtin_amdgcn_mfma_f32_16x16x32_bf16(alo[kt], whi, acc[ct], 0, 0, 0);
            acc[ct] = __builtin_amdgcn_mfma_f32_16x16x32_bf16(ahi[kt], wlo, acc[ct], 0, 0, 0);
            acc[ct] = __builtin_amdgcn_mfma_f32_16x16x32_bf16(ahi[kt], whi, acc[ct], 0, 0, 0);
        }
    }

    // store H (C/D layout: col=m, row=quad*4+r)
    int growbase = blockIdx.x * 64 + wv * 16 + quad * 4;
#pragma unroll
    for (int r = 0; r < 4; r++) {
        int gr = growbase + r;
        if (gr < N) {
#pragma unroll
            for (int ct = 0; ct < 8; ct++)
                H[(size_t)gr * D + ct * 16 + m] = acc[ct][r];
        }
    }

    // fused dots: reduce over the 16 lanes of each quad
    float ps[4] = {0, 0, 0, 0}, pd[4] = {0, 0, 0, 0};
#pragma unroll
    for (int ct = 0; ct < 8; ct++) {
        float as_v = avS[ct * 16 + m];
        float ad_v = avD[ct * 16 + m];
#pragma unroll
        for (int r = 0; r < 4; r++) {
            ps[r] += acc[ct][r] * as_v;
            pd[r] += acc[ct][r] * ad_v;
        }
    }
    for (int o = 1; o < 16; o <<= 1) {
#pragma unroll
        for (int r = 0; r < 4; r++) {
            ps[r] += __shfl_xor(ps[r], o, 64);
            pd[r] += __shfl_xor(pd[r], o, 64);
        }
    }
    if (m == 0) {
#pragma unroll
        for (int r = 0; r < 4; r++) {
            int gr = growbase + r;
            if (gr < N) { sA[gr] = ps[r]; dA[gr] = pd[r]; }
        }
    }
}

// ---------------- fused softmax + aggregation: one wave per dst ----------------------

template <bool ACT>
__global__ __launch_bounds__(256) void k_agg(const float* __restrict__ H,
                                             const float* __restrict__ sA,
                                             const float* __restrict__ dA,
                                             const int* __restrict__ rowptr,
                                             const int* __restrict__ csr,
                                             const float* __restrict__ bias,
                                             float* __restrict__ out, int N) {
    int lane = threadIdx.x & 63;
    int node = blockIdx.x * 4 + (threadIdx.x >> 6);
    if (node >= N) return;
    int start = __builtin_amdgcn_readfirstlane(rowptr[node]);
    int end   = __builtin_amdgcn_readfirstlane(rowptr[node + 1]);
    float di  = dA[node];
    int half  = lane >> 5;
    int cq    = (lane & 31) * 4;

    float ax = 0.f, ay = 0.f, az = 0.f, aw = 0.f;
    float den = 0.f;
    int j = start;
    for (; j + 4 <= end; j += 4) {
        int s0 = csr[j + 0], s1 = csr[j + 1], s2 = csr[j + 2], s3 = csr[j + 3];
        float e0 = sA[s0] + di, e1 = sA[s1] + di, e2 = sA[s2] + di, e3 = sA[s3] + di;
        e0 = (e0 > 0.f) ? e0 : 0.2f * e0;
        e1 = (e1 > 0.f) ? e1 : 0.2f * e1;
        e2 = (e2 > 0.f) ? e2 : 0.2f * e2;
        e3 = (e3 > 0.f) ? e3 : 0.2f * e3;
        float p0 = __expf(e0), p1 = __expf(e1), p2 = __expf(e2), p3 = __expf(e3);
        int   sa = half ? s1 : s0;
        int   sb = half ? s3 : s2;
        float wa = half ? p1 : p0;
        float wb = half ? p3 : p2;
        den += wa + wb;
        float4 ha = *(const float4*)&H[(size_t)sa * D + cq];
        float4 hb = *(const float4*)&H[(size_t)sb * D + cq];
        ax += wa * ha.x + wb * hb.x;
        ay += wa * ha.y + wb * hb.y;
        az += wa * ha.z + wb * hb.z;
        aw += wa * ha.w + wb * hb.w;
    }
    if (j + 2 <= end) {
        int s0 = csr[j + 0], s1 = csr[j + 1];
        float e0 = sA[s0] + di, e1 = sA[s1] + di;
        e0 = (e0 > 0.f) ? e0 : 0.2f * e0;
        e1 = (e1 > 0.f) ? e1 : 0.2f * e1;
        float p0 = __expf(e0), p1 = __expf(e1);
        int   sa = half ? s1 : s0;
        float wa = half ? p1 : p0;
        den += wa;
        float4 ha = *(const float4*)&H[(size_t)sa * D + cq];
        ax += wa * ha.x; ay += wa * ha.y; az += wa * ha.z; aw += wa * ha.w;
        j += 2;
    }
    if (j < end && half == 0) {
        int s0 = csr[j];
        float e0 = sA[s0] + di;
        e0 = (e0 > 0.f) ? e0 : 0.2f * e0;
        float p0 = __expf(e0);
        den += p0;
        float4 ha = *(const float4*)&H[(size_t)s0 * D + cq];
        ax += p0 * ha.x; ay += p0 * ha.y; az += p0 * ha.z; aw += p0 * ha.w;
    }

    ax  += __shfl_xor(ax, 32, 64);
    ay  += __shfl_xor(ay, 32, 64);
    az  += __shfl_xor(az, 32, 64);
    aw  += __shfl_xor(aw, 32, 64);
    den += __shfl_xor(den, 32, 64);

    if (half == 0) {
        float iv = 1.f / den;
        float4 b4 = *(const float4*)&bias[cq];
        float vx = ax * iv + b4.x;
        float vy = ay * iv + b4.y;
        float vz = az * iv + b4.z;
        float vw = aw * iv + b4.w;
        if (ACT) {
            vx = 2.f * tanhf(vx);
            vy = 2.f * tanhf(vy);
            vz = 2.f * tanhf(vz);
            vw = 2.f * tanhf(vw);
        }
        *(float4*)&out[(size_t)node * D + cq] = make_float4(vx, vy, vz, vw);
    }
}

// ---------------- launch ----------------

extern "C" void kernel_launch(void* const* d_in, const int* in_sizes, int n_in,
                              void* d_out, int out_size, void* d_ws, size_t ws_size,
                              hipStream_t stream) {
    const int N = in_sizes[0] / D;
    const int E = in_sizes[1] / 2;
    const float* x = (const float*)d_in[0];
    const int* ei = (const int*)d_in[1];
    const float* Wm[3] = {(const float*)d_in[2], (const float*)d_in[6], (const float*)d_in[10]};
    const float* aS[3] = {(const float*)d_in[3], (const float*)d_in[7], (const float*)d_in[11]};
    const float* aD[3] = {(const float*)d_in[4], (const float*)d_in[8], (const float*)d_in[12]};
    const float* bb[3] = {(const float*)d_in[5], (const float*)d_in[9], (const float*)d_in[13]};

    char* ws = (char*)d_ws;
    size_t off = 0;
    auto alloc = [&](size_t bytes) -> void* {
        void* p = ws + off;
        off = (off + bytes + 511) & ~(size_t)511;
        return p;
    };
    float* bufA  = (float*)alloc((size_t)N * D * 4);
    float* bufB  = (float*)alloc((size_t)N * D * 4);
    float* sArr  = (float*)alloc((size_t)N * 4);
    float* dArr  = (float*)alloc((size_t)N * 4);
    int*   deg   = (int*)alloc((size_t)N * 4);
    int*   rowptr= (int*)alloc((size_t)(N + 1) * 4);
    int*   tmp   = (int*)alloc((size_t)N * 4);
    int*   bsum  = (int*)alloc(256 * 4);
    int*   csr   = (int*)alloc((size_t)(E + N) * 4);
    unsigned short* whiB = (unsigned short*)alloc((size_t)3 * D * D * 2);
    unsigned short* wloB = (unsigned short*)alloc((size_t)3 * D * D * 2);
    (void)ws_size; (void)n_in; (void)out_size;

    const int B1 = (N + 255) / 256;

    k_init_deg<<<B1, 256, 0, stream>>>(deg, N);
    k_count<<<1024, 256, 0, stream>>>(ei, E, N, deg);
    k_scan1<<<B1, 256, 0, stream>>>(deg, N, tmp, bsum);
    k_scan2<<<1, 256, 0, stream>>>(bsum, B1);
    k_scan3<<<B1, 256, 0, stream>>>(tmp, bsum, N, E + N, rowptr, deg);
    k_fill<<<1024, 256, 0, stream>>>(ei, E, N, deg, csr);

    k_wpack3<<<24, 256, 0, stream>>>(Wm[0], Wm[1], Wm[2], whiB, wloB);

    const int gemmBlocks = (N + 63) / 64;
    for (int l = 0; l < 3; l++) {
        const unsigned short* whi = whiB + (size_t)l * 16384;
        const unsigned short* wlo = wloB + (size_t)l * 16384;
        if (l == 0) {
            k_gemm<true><<<gemmBlocks, 256, 0, stream>>>(x, whi, wlo, aS[0], aD[0],
                                                         bufB, sArr, dArr, N);
        } else {
            k_gemm<false><<<gemmBlocks, 256, 0, stream>>>(bufA, whi, wlo, aS[l], aD[l],
                                                          bufB, sArr, dArr, N);
        }
        if (l < 2) {
            k_agg<true><<<(N + 3) / 4, 256, 0, stream>>>(bufB, sArr, dArr, rowptr, csr,
                                                         bb[l], bufA, N);
        } else {
            k_agg<false><<<(N + 3) / 4, 256, 0, stream>>>(bufB, sArr, dArr, rowptr, csr,
                                                          bb[l], (float*)d_out, N);
        }
    }
}